// Round 12
// baseline (9767.825 us; speedup 1.0000x reference)
//
#include <hip/hip_runtime.h>
#include <stdint.h>
#include <stddef.h>

#define B_ 16
#define T_ 1024
#define F_ 80
#define D_ 512
#define M_ 16384   // T*B rows, row index = t*16 + b
#define VO 29      // V+1
#define SENT 0x7FC07FC0u
#define RPH 5      // h-ring phases (5 -> crew-ack gate has 2 periods of slack)

typedef float f32x4 __attribute__((ext_vector_type(4)));
typedef short s16x8 __attribute__((ext_vector_type(8)));
typedef unsigned short u16x8 __attribute__((ext_vector_type(8)));

static __device__ __forceinline__ unsigned short f2bf(float f) {
    union { float f; unsigned u; } v; v.f = f;
    unsigned r = v.u + 0x7FFFu + ((v.u >> 16) & 1u);
    return (unsigned short)(r >> 16);
}
static __device__ __forceinline__ float bf2f(unsigned short h) {
    union { unsigned u; float f; } v; v.u = ((unsigned)h) << 16; return v.f;
}
static __device__ __forceinline__ void split2(float v, unsigned short& hi, unsigned short& lo) {
    hi = f2bf(v);
    lo = f2bf(v - bf2f(hi));
}
static __device__ __forceinline__ float sigm(float x) {
    return 1.0f / (1.0f + __expf(-x));
}
static __device__ __forceinline__ float fast_tanh(float x) {
    return 1.0f - 2.0f / (__expf(2.0f * x) + 1.0f);
}
static __device__ __forceinline__ float wred(float v) {
    #pragma unroll
    for (int off = 1; off < 64; off <<= 1) v += __shfl_xor(v, off, 64);
    return v;
}
static __device__ __forceinline__ float ldf_agent(const float* p) {
    unsigned u = __hip_atomic_load((const unsigned*)p, __ATOMIC_RELAXED, __HIP_MEMORY_SCOPE_AGENT);
    union { unsigned u; float f; } c; c.u = u; return c.f;
}
static __device__ __forceinline__ void stf_agent(float* p, float v) {
    union { float f; unsigned u; } c; c.f = v;
    __hip_atomic_store((unsigned*)p, c.u, __ATOMIC_RELAXED, __HIP_MEMORY_SCOPE_AGENT);
}
// async global->LDS, 16B per lane
static __device__ __forceinline__ void gload16(const void* g, void* lds) {
    __builtin_amdgcn_global_load_lds(
        (const __attribute__((address_space(1))) void*)g,
        (__attribute__((address_space(3))) void*)lds, 16, 0, 0);
}

// ---------------- weight conversion (fp32 -> bf16 hi/lo split) ----------------
__global__ __launch_bounds__(256) void conv_w0(const float* __restrict__ W,
        unsigned short* __restrict__ Bh, unsigned short* __restrict__ Bl) {
    int gid = blockIdx.x * 256 + threadIdx.x;     // 2048*96
    int n = gid / 96, k = gid - n * 96;
    float v = (k < 80) ? W[(size_t)k * 2048 + n] : 0.0f;
    unsigned short h, l; split2(v, h, l);
    Bh[gid] = h; Bl[gid] = l;
}
__global__ __launch_bounds__(256) void conv_sruw1(const float* __restrict__ W,
        unsigned short* __restrict__ Bh, unsigned short* __restrict__ Bl) {
    int gid = blockIdx.x * 256 + threadIdx.x;     // 1536*512
    int n = gid >> 9, k = gid & 511;
    float v = W[(size_t)k * 1536 + n];
    unsigned short h, lo; split2(v, h, lo);
    Bh[gid] = h; Bl[gid] = lo;
}
__global__ __launch_bounds__(256) void conv_split(const float* __restrict__ W,
        unsigned short* __restrict__ Oh, unsigned short* __restrict__ Ol, int n) {
    int gid = blockIdx.x * 256 + threadIdx.x;
    if (gid < n) {
        unsigned short h, l; split2(W[gid], h, l);
        Oh[gid] = h; Ol[gid] = l;
    }
}
__global__ __launch_bounds__(256) void sent_fill(unsigned int* __restrict__ buf, int n) {
    int gid = blockIdx.x * 256 + threadIdx.x;
    if (gid < n)
        __hip_atomic_store(&buf[gid], SENT, __ATOMIC_RELAXED, __HIP_MEMORY_SCOPE_AGENT);
}
__global__ void zero_ctl(unsigned int* c) {
    if (threadIdx.x < 160)
        __hip_atomic_store(&c[threadIdx.x], 0u, __ATOMIC_RELAXED, __HIP_MEMORY_SCOPE_AGENT);
}

// ---------------- LayerNorm kernels ----------------
__global__ __launch_bounds__(256) void ln80_kernel(const float* __restrict__ x,
        const float* __restrict__ g, const float* __restrict__ bta,
        unsigned short* __restrict__ xh, unsigned short* __restrict__ xl) {
    int w = threadIdx.x >> 6, lane = threadIdx.x & 63;
    int row = blockIdx.x * 4 + w;          // row = t*16 + b
    int b = row & 15, t = row >> 4;
    const float* xr = x + ((size_t)b * T_ + t) * F_;
    float v0 = xr[lane];
    float v1 = (lane < 16) ? xr[64 + lane] : 0.0f;
    float mean = wred(v0 + v1) * (1.0f / 80.0f);
    float d0 = v0 - mean;
    float d1 = (lane < 16) ? (v1 - mean) : 0.0f;
    float var = wred(d0 * d0 + d1 * d1) * (1.0f / 80.0f);
    float rstd = rsqrtf(var + 1e-5f);
    float o0 = d0 * rstd * g[lane] + bta[lane];
    unsigned short h, l; split2(o0, h, l);
    xh[(size_t)row * 96 + lane] = h;
    xl[(size_t)row * 96 + lane] = l;
    if (lane < 32) {
        unsigned short hv = 0, lv = 0;
        if (lane < 16) {
            float o1 = d1 * rstd * g[64 + lane] + bta[64 + lane];
            split2(o1, hv, lv);
        }
        xh[(size_t)row * 96 + 64 + lane] = hv;
        xl[(size_t)row * 96 + 64 + lane] = lv;
    }
}

__global__ __launch_bounds__(256) void ln512_bf16(const float* __restrict__ hsrc,
        const float* __restrict__ g, const float* __restrict__ bta,
        unsigned short* __restrict__ oh, unsigned short* __restrict__ ol) {
    int w = threadIdx.x >> 6, lane = threadIdx.x & 63;
    size_t row = (size_t)blockIdx.x * 4 + w;
    const float* hr = hsrc + row * D_;
    float4 p0 = *(const float4*)(hr + lane * 8);
    float4 p1 = *(const float4*)(hr + lane * 8 + 4);
    float s = p0.x + p0.y + p0.z + p0.w + p1.x + p1.y + p1.z + p1.w;
    float mean = wred(s) * (1.0f / 512.0f);
    float d[8] = {p0.x - mean, p0.y - mean, p0.z - mean, p0.w - mean,
                  p1.x - mean, p1.y - mean, p1.z - mean, p1.w - mean};
    float q = 0.f;
    #pragma unroll
    for (int i = 0; i < 8; ++i) q += d[i] * d[i];
    float rstd = rsqrtf(wred(q) * (1.0f / 512.0f) + 1e-5f);
    const float* gp = g + lane * 8;
    const float* bp = bta + lane * 8;
    u16x8 vh, vl;
    #pragma unroll
    for (int i = 0; i < 8; ++i) {
        float o = d[i] * rstd * gp[i] + bp[i];
        unsigned short hh, ll; split2(o, hh, ll);
        vh[i] = hh; vl[i] = ll;
    }
    *(u16x8*)(oh + row * D_ + lane * 8) = vh;
    *(u16x8*)(ol + row * D_ + lane * 8) = vl;
}

__global__ __launch_bounds__(256) void ln512_f32(const float* __restrict__ hsrc,
        const float* __restrict__ g, const float* __restrict__ bta,
        float* __restrict__ o) {
    int w = threadIdx.x >> 6, lane = threadIdx.x & 63;
    size_t row = (size_t)blockIdx.x * 4 + w;
    const float* hr = hsrc + row * D_;
    float4 p0 = *(const float4*)(hr + lane * 8);
    float4 p1 = *(const float4*)(hr + lane * 8 + 4);
    float s = p0.x + p0.y + p0.z + p0.w + p1.x + p1.y + p1.z + p1.w;
    float mean = wred(s) * (1.0f / 512.0f);
    float d[8] = {p0.x - mean, p0.y - mean, p0.z - mean, p0.w - mean,
                  p1.x - mean, p1.y - mean, p1.z - mean, p1.w - mean};
    float q = 0.f;
    #pragma unroll
    for (int i = 0; i < 8; ++i) q += d[i] * d[i];
    float rstd = rsqrtf(wred(q) * (1.0f / 512.0f) + 1e-5f);
    const float* gp = g + lane * 8;
    const float* bp = bta + lane * 8;
    float* op = o + row * D_ + lane * 8;
    #pragma unroll
    for (int i = 0; i < 8; ++i) op[i] = d[i] * rstd * gp[i] + bp[i];
}

// ------- split bf16 MFMA GEMM, 128x128 tile, global_load_lds + XOR swizzle -------
__global__ __launch_bounds__(256) void gemm_split(
        const unsigned short* __restrict__ Ah, const unsigned short* __restrict__ Al,
        const unsigned short* __restrict__ Bh, const unsigned short* __restrict__ Bl,
        float* __restrict__ C, int N, int Kp,
        const float* __restrict__ bias0, const float* __restrict__ bias1) {
    __shared__ __align__(16) unsigned short sAh[4096];
    __shared__ __align__(16) unsigned short sAl[4096];
    __shared__ __align__(16) unsigned short sBh[4096];
    __shared__ __align__(16) unsigned short sBl[4096];
    const int tid = threadIdx.x;
    const int wv = tid >> 6, lane = tid & 63;
    const int c_ = lane & 15, r_ = lane >> 4;
    const int wr = wv >> 1, wc = wv & 1;
    const int mBase = blockIdx.y * 128, nBase = blockIdx.x * 128;

    const int row0 = tid >> 2, row1 = 64 + row0;
    const int sp = tid & 3;
    const int x0 = (row0 & 3) ^ ((row0 >> 2) & 3);
    const int x1 = (row1 & 3) ^ ((row1 >> 2) & 3);
    const size_t gA0 = (size_t)(mBase + row0) * Kp + (size_t)((sp ^ x0) * 8);
    const size_t gA1 = (size_t)(mBase + row1) * Kp + (size_t)((sp ^ x1) * 8);
    const size_t gB0 = (size_t)(nBase + row0) * Kp + (size_t)((sp ^ x0) * 8);
    const size_t gB1 = (size_t)(nBase + row1) * Kp + (size_t)((sp ^ x1) * 8);
    const int ldsW = wv * 1024;

    int offA[4], offB[4];
    #pragma unroll
    for (int f = 0; f < 4; ++f) {
        int ra = wr * 64 + f * 16 + c_;
        int xa = (ra & 3) ^ ((ra >> 2) & 3);
        offA[f] = ra * 32 + ((r_ ^ xa) * 8);
        int rb = wc * 64 + f * 16 + c_;
        int xb = (rb & 3) ^ ((rb >> 2) & 3);
        offB[f] = rb * 32 + ((r_ ^ xb) * 8);
    }

    f32x4 acc[4][4] = {};
    for (int kt = 0; kt < Kp; kt += 32) {
        gload16(Ah + gA0 + kt, (char*)sAh + ldsW);
        gload16(Ah + gA1 + kt, (char*)sAh + 4096 + ldsW);
        gload16(Al + gA0 + kt, (char*)sAl + ldsW);
        gload16(Al + gA1 + kt, (char*)sAl + 4096 + ldsW);
        gload16(Bh + gB0 + kt, (char*)sBh + ldsW);
        gload16(Bh + gB1 + kt, (char*)sBh + 4096 + ldsW);
        gload16(Bl + gB0 + kt, (char*)sBl + ldsW);
        gload16(Bl + gB1 + kt, (char*)sBl + 4096 + ldsW);
        __syncthreads();
        s16x8 ah[4], al[4], bh[4], bl[4];
        #pragma unroll
        for (int f = 0; f < 4; ++f) {
            ah[f] = *(const s16x8*)&sAh[offA[f]];
            al[f] = *(const s16x8*)&sAl[offA[f]];
            bh[f] = *(const s16x8*)&sBh[offB[f]];
            bl[f] = *(const s16x8*)&sBl[offB[f]];
        }
        #pragma unroll
        for (int mf = 0; mf < 4; ++mf) {
            #pragma unroll
            for (int nf = 0; nf < 4; ++nf) {
                acc[mf][nf] = __builtin_amdgcn_mfma_f32_16x16x32_bf16(ah[mf], bh[nf], acc[mf][nf], 0, 0, 0);
                acc[mf][nf] = __builtin_amdgcn_mfma_f32_16x16x32_bf16(al[mf], bh[nf], acc[mf][nf], 0, 0, 0);
                acc[mf][nf] = __builtin_amdgcn_mfma_f32_16x16x32_bf16(ah[mf], bl[nf], acc[mf][nf], 0, 0, 0);
            }
        }
        __syncthreads();
    }
    #pragma unroll
    for (int mf = 0; mf < 4; ++mf) {
        #pragma unroll
        for (int r = 0; r < 4; ++r) {
            int m = mBase + wr * 64 + mf * 16 + r_ * 4 + r;
            float* crow = C + (size_t)m * N + nBase + wc * 64;
            #pragma unroll
            for (int nf = 0; nf < 4; ++nf) {
                int n = nBase + wc * 64 + nf * 16 + c_;
                float v = acc[mf][nf][r];
                if (bias0) v += bias0[n];
                if (bias1) v += bias1[n];
                crow[nf * 16 + c_] = v;
            }
        }
    }
}

// ---------------- SRU recurrence ----------------
__global__ __launch_bounds__(64) void sru_rec(const float* __restrict__ U, int NU,
        const float* __restrict__ xprev, const float* __restrict__ wc,
        const float* __restrict__ bias, float* __restrict__ hout) {
    int gid = blockIdx.x * 64 + threadIdx.x;
    int d = gid & (D_ - 1), b = gid >> 9;
    float vf = wc[d], vr = wc[D_ + d];
    float bf = bias[d], br = bias[D_ + d];
    const float* u0 = U + d;
    const float* u1 = U + D_ + d;
    const float* u2 = U + 2 * D_ + d;
    const float* xr;  size_t xstride;
    if (xprev) { xr = xprev + d; xstride = D_; }
    else       { xr = U + 3 * (size_t)D_ + d; xstride = (size_t)NU; }
    float* ho = hout + d;
    float c = 0.f;
    #pragma unroll 4
    for (int t = 0; t < T_; ++t) {
        size_t row = (size_t)(t * 16 + b);
        float a0 = u0[row * NU];
        float a1 = u1[row * NU];
        float a2 = u2[row * NU];
        float xv = xr[row * xstride];
        float f = sigm(a1 + vf * c + bf);
        float r = sigm(a2 + vr * c + br);
        c = f * c + (1.f - f) * a0;
        float h = r * c + (1.f - r) * xv;
        ho[row * D_] = h;
    }
}

// =================== 3-layer pipelined LSTM (persistent, 112 WGs) ===================
// Roles: [0,16) LSTM L0 | [16,32) L1 | [32,48) L2 | [48,80) crew1 | [80,112) crew2.
// CHANGE (r12): h-rings widened 3 -> 5 phases; producer's crew-ack gate relaxed
// from cprog>=t-1 to cprog>=t-3 (reset slot now holds h_{t-4}) -> the crew-ack
// round-trip leaves the recurrence-critical path (2 periods of slack).

template <int MODE>
static __device__ void lstm_role(int wg, const float* gxsrc,
        const unsigned short* Wh, const unsigned short* Wl,
        unsigned* ring, const unsigned* crewflags, unsigned* myLprog,
        const unsigned* consCprog, float* hout) {
    __shared__ __align__(16) unsigned short hH[16][520];
    __shared__ __align__(16) unsigned short hL[16][520];
    __shared__ float G[16][132];
    const int tid = threadIdx.x;
    const int w = tid >> 6, lane = tid & 63;
    const int c_ = lane & 15, r_ = lane >> 4;

    s16x8 bh0[16], bh1[16], bl0[16], bl1[16];
    {
        size_t R0 = (size_t)(w * 512 + wg * 32 + c_) * 512;
        size_t R1 = R0 + 16 * 512;
        #pragma unroll
        for (int ks = 0; ks < 16; ++ks) {
            bh0[ks] = *(const s16x8*)(Wh + R0 + ks * 32 + r_ * 8);
            bh1[ks] = *(const s16x8*)(Wh + R1 + ks * 32 + r_ * 8);
            bl0[ks] = *(const s16x8*)(Wl + R0 + ks * 32 + r_ * 8);
            bl1[ks] = *(const s16x8*)(Wl + R1 + ks * 32 + r_ * 8);
        }
    }
    for (int i = tid; i < 16 * 520; i += 256) {
        ((unsigned short*)hH)[i] = 0;
        ((unsigned short*)hL)[i] = 0;
    }
    const int eb = tid >> 4;
    const int ed = (tid * 2) & 31;
    float cc0 = 0.f, cc1 = 0.f;
    const int col0 = w * 512 + wg * 32 + c_;
    const int hidx = (eb * 512 + wg * 32 + ed) >> 1;

    float gxv0[4], gxv1[4];
    if (MODE == 0) {
        #pragma unroll
        for (int r = 0; r < 4; ++r) {
            int bt = r_ * 4 + r;
            gxv0[r] = gxsrc[(size_t)bt * 2048 + col0];
            gxv1[r] = gxsrc[(size_t)bt * 2048 + col0 + 16];
        }
    } else {
        while (true) {
            int f = (int)__hip_atomic_load(&crewflags[lane & 31],
                                           __ATOMIC_RELAXED, __HIP_MEMORY_SCOPE_AGENT);
            if (__all(f >= 1)) break;
            __builtin_amdgcn_s_sleep(1);
        }
        #pragma unroll
        for (int r = 0; r < 4; ++r) {
            int bt = r_ * 4 + r;
            gxv0[r] = ldf_agent(gxsrc + (size_t)bt * 2048 + col0);
            gxv1[r] = ldf_agent(gxsrc + (size_t)bt * 2048 + col0 + 16);
        }
    }
    int cph = 0;   // phase index = t % RPH
    __syncthreads();

    for (int t = 0; t < T_; ++t) {
        const int pcur = cph * 8192;
        const int pnxt = ((cph + 1 == RPH) ? 0 : cph + 1) * 8192;
        if (MODE == 1 && tid == 0)
            __hip_atomic_store(&myLprog[wg], (unsigned)t, __ATOMIC_RELAXED, __HIP_MEMORY_SCOPE_AGENT);
        // crew-ack gate: reset slot holds h_{t-4}; crew must have consumed it
        if (consCprog) {
            int lim = t - 3;
            while (true) {
                int p = (int)__hip_atomic_load(&consCprog[lane & 31],
                                               __ATOMIC_RELAXED, __HIP_MEMORY_SCOPE_AGENT);
                if (__all(p >= lim)) break;
                __builtin_amdgcn_s_sleep(2);
            }
        }
        __hip_atomic_store(&ring[pnxt + hidx], SENT, __ATOMIC_RELAXED, __HIP_MEMORY_SCOPE_AGENT);
        __hip_atomic_store(&ring[pnxt + 4096 + hidx], SENT, __ATOMIC_RELAXED, __HIP_MEMORY_SCOPE_AGENT);
        f32x4 acc0 = {0.f, 0.f, 0.f, 0.f};
        f32x4 acc1 = {0.f, 0.f, 0.f, 0.f};
        #pragma unroll
        for (int ks = 0; ks < 16; ++ks) {
            s16x8 ah = *(const s16x8*)&hH[c_][ks * 32 + r_ * 8];
            s16x8 al = *(const s16x8*)&hL[c_][ks * 32 + r_ * 8];
            acc0 = __builtin_amdgcn_mfma_f32_16x16x32_bf16(ah, bh0[ks], acc0, 0, 0, 0);
            acc1 = __builtin_amdgcn_mfma_f32_16x16x32_bf16(ah, bh1[ks], acc1, 0, 0, 0);
            acc0 = __builtin_amdgcn_mfma_f32_16x16x32_bf16(al, bh0[ks], acc0, 0, 0, 0);
            acc1 = __builtin_amdgcn_mfma_f32_16x16x32_bf16(al, bh1[ks], acc1, 0, 0, 0);
            acc0 = __builtin_amdgcn_mfma_f32_16x16x32_bf16(ah, bl0[ks], acc0, 0, 0, 0);
            acc1 = __builtin_amdgcn_mfma_f32_16x16x32_bf16(ah, bl1[ks], acc1, 0, 0, 0);
        }
        #pragma unroll
        for (int r = 0; r < 4; ++r) {
            int bt = r_ * 4 + r;
            G[bt][w * 32 + c_]      = acc0[r] + gxv0[r];
            G[bt][w * 32 + 16 + c_] = acc1[r] + gxv1[r];
        }
        __syncthreads();
        float iv0 = G[eb][ed],     fv0 = G[eb][32 + ed], gv0 = G[eb][64 + ed], ov0 = G[eb][96 + ed];
        float iv1 = G[eb][ed + 1], fv1 = G[eb][33 + ed], gv1 = G[eb][65 + ed], ov1 = G[eb][97 + ed];
        cc0 = sigm(fv0) * cc0 + sigm(iv0) * fast_tanh(gv0);
        cc1 = sigm(fv1) * cc1 + sigm(iv1) * fast_tanh(gv1);
        float h0 = sigm(ov0) * fast_tanh(cc0);
        float h1 = sigm(ov1) * fast_tanh(cc1);
        asm volatile("s_waitcnt vmcnt(0)" ::: "memory");
        unsigned short h0h, h0l, h1h, h1l;
        split2(h0, h0h, h0l); split2(h1, h1h, h1l);
        unsigned packH = (unsigned)h0h | ((unsigned)h1h << 16);
        unsigned packL = (unsigned)h0l | ((unsigned)h1l << 16);
        __hip_atomic_store(&ring[pcur + hidx], packH, __ATOMIC_RELAXED, __HIP_MEMORY_SCOPE_AGENT);
        __hip_atomic_store(&ring[pcur + 4096 + hidx], packL, __ATOMIC_RELAXED, __HIP_MEMORY_SCOPE_AGENT);
        if (hout) {
            size_t orow = (size_t)(t * 16 + eb) * D_ + wg * 32 + ed;
            hout[orow] = h0; hout[orow + 1] = h1;
        }
        if (t == T_ - 1) break;
        // prefetch gx_{t+1} (free for MODE 0; flag-gated speculative for MODE 1)
        if (MODE == 0) {
            const float* gxr = gxsrc + (size_t)((t + 1) * 16) * 2048;
            #pragma unroll
            for (int r = 0; r < 4; ++r) {
                int bt = r_ * 4 + r;
                gxv0[r] = gxr[(size_t)bt * 2048 + col0];
                gxv1[r] = gxr[(size_t)bt * 2048 + col0 + 16];
            }
        } else {
            int need = t + 2;
            while (true) {
                int f = (int)__hip_atomic_load(&crewflags[lane & 31],
                                               __ATOMIC_RELAXED, __HIP_MEMORY_SCOPE_AGENT);
                if (__all(f >= need)) break;
                __builtin_amdgcn_s_sleep(1);
            }
            const float* gs = gxsrc + (size_t)((t + 1) & 3) * 32768;
            #pragma unroll
            for (int r = 0; r < 4; ++r) {
                int bt = r_ * 4 + r;
                gxv0[r] = ldf_agent(gs + (size_t)bt * 2048 + col0);
                gxv1[r] = ldf_agent(gs + (size_t)bt * 2048 + col0 + 16);
            }
        }
        // ---- sentinel poll with repair re-reads ----
        unsigned long long vh[8], vl[8];
        unsigned badm = 0xFFFFu;
        while (true) {
            #pragma unroll
            for (int j = 0; j < 8; ++j) {
                int q = pcur + j * 512 + tid * 2;
                if (badm & (1u << j))
                    vh[j] = __hip_atomic_load((const unsigned long long*)&ring[q],
                                              __ATOMIC_RELAXED, __HIP_MEMORY_SCOPE_AGENT);
                if (badm & (1u << (8 + j)))
                    vl[j] = __hip_atomic_load((const unsigned long long*)&ring[q + 4096],
                                              __ATOMIC_RELAXED, __HIP_MEMORY_SCOPE_AGENT);
            }
            unsigned nb = 0u;
            #pragma unroll
            for (int j = 0; j < 8; ++j) {
                unsigned a0 = (unsigned)vh[j], a1 = (unsigned)(vh[j] >> 32);
                unsigned b0 = (unsigned)vl[j], b1 = (unsigned)(vl[j] >> 32);
                if (((a0 >> 16) == 0x7FC0u) || ((a1 >> 16) == 0x7FC0u)) nb |= 1u << j;
                if (((b0 >> 16) == 0x7FC0u) || ((b1 >> 16) == 0x7FC0u)) nb |= 1u << (8 + j);
            }
            badm = nb;
            if (!__any(badm != 0u)) break;
            __builtin_amdgcn_s_sleep(1);
        }
        #pragma unroll
        for (int j = 0; j < 8; ++j) {
            int q = j * 512 + tid * 2;
            int bb = q >> 8, dd = (q & 255) * 2;
            *(unsigned long long*)&hH[bb][dd] = vh[j];
            *(unsigned long long*)&hL[bb][dd] = vl[j];
        }
        __syncthreads();
        cph = (cph + 1 == RPH) ? 0 : cph + 1;
    }
}

// crew: per step, LN(h^l_t) then gx^{l+1}_t tile (64 cols) via 3-term MFMA
static __device__ void crew_role(int cid, const unsigned* srcring, float* gxr,
        unsigned* flags, unsigned* cprog, const unsigned* lprog,
        const unsigned short* WihHp, const unsigned short* WihLp,
        const float* g, const float* bta,
        const float* bihp, const float* bhhp) {
    __shared__ __align__(16) unsigned short xnH[16][520];
    __shared__ __align__(16) unsigned short xnL[16][520];
    const int tid = threadIdx.x;
    const int w = tid >> 6, lane = tid & 63;
    const int c_ = lane & 15, r_ = lane >> 4;
    const int col = cid * 64 + w * 16 + c_;
    const int rr = w * 4 + r_;          // LN row owned by this lane

    s16x8 bfh[16], bfl[16];
    {
        const unsigned short* wrH = WihHp + (size_t)col * 512;
        const unsigned short* wrL = WihLp + (size_t)col * 512;
        #pragma unroll
        for (int ks = 0; ks < 16; ++ks) {
            bfh[ks] = *(const s16x8*)(wrH + ks * 32 + r_ * 8);
            bfl[ks] = *(const s16x8*)(wrL + ks * 32 + r_ * 8);
        }
    }
    const float bias = bihp[col] + bhhp[col];
    float lg[32], lb[32];
    #pragma unroll
    for (int j = 0; j < 32; ++j) { lg[j] = g[c_ * 32 + j]; lb[j] = bta[c_ * 32 + j]; }

    int cph = 0;   // phase index = t % RPH
    for (int t = 0; t < T_; ++t) {
        // sentinel-poll h^l_t (own LN window) with repair re-reads
        const unsigned* sb = srcring + cph * 8192;
        const int qi = rr * 256 + c_ * 16;
        unsigned long long vh[8], vl[8];
        unsigned badm = 0xFFFFu;
        while (true) {
            #pragma unroll
            for (int j = 0; j < 8; ++j) {
                if (badm & (1u << j))
                    vh[j] = __hip_atomic_load((const unsigned long long*)&sb[qi + j * 2],
                                              __ATOMIC_RELAXED, __HIP_MEMORY_SCOPE_AGENT);
                if (badm & (1u << (8 + j)))
                    vl[j] = __hip_atomic_load((const unsigned long long*)&sb[4096 + qi + j * 2],
                                              __ATOMIC_RELAXED, __HIP_MEMORY_SCOPE_AGENT);
            }
            unsigned nb = 0u;
            #pragma unroll
            for (int j = 0; j < 8; ++j) {
                unsigned a0 = (unsigned)vh[j], a1 = (unsigned)(vh[j] >> 32);
                unsigned b0 = (unsigned)vl[j], b1 = (unsigned)(vl[j] >> 32);
                if (((a0 >> 16) == 0x7FC0u) || ((a1 >> 16) == 0x7FC0u)) nb |= 1u << j;
                if (((b0 >> 16) == 0x7FC0u) || ((b1 >> 16) == 0x7FC0u)) nb |= 1u << (8 + j);
            }
            badm = nb;
            if (!__any(badm != 0u)) break;
            __builtin_amdgcn_s_sleep(1);
        }
        // reconstruct 32 fp32 values
        float x[32];
        #pragma unroll
        for (int k = 0; k < 8; ++k) {
            unsigned ah = (unsigned)vh[k], bh = (unsigned)(vh[k] >> 32);
            unsigned al = (unsigned)vl[k], bl = (unsigned)(vl[k] >> 32);
            x[4 * k + 0] = bf2f((unsigned short)ah) + bf2f((unsigned short)al);
            x[4 * k + 1] = bf2f((unsigned short)(ah >> 16)) + bf2f((unsigned short)(al >> 16));
            x[4 * k + 2] = bf2f((unsigned short)bh) + bf2f((unsigned short)bl);
            x[4 * k + 3] = bf2f((unsigned short)(bh >> 16)) + bf2f((unsigned short)(bl >> 16));
        }
        // LN across the 16-lane row group
        float s = 0.f;
        #pragma unroll
        for (int j = 0; j < 32; ++j) s += x[j];
        #pragma unroll
        for (int m = 1; m < 16; m <<= 1) s += __shfl_xor(s, m, 64);
        float mean = s * (1.0f / 512.0f);
        float q = 0.f;
        #pragma unroll
        for (int j = 0; j < 32; ++j) { float d = x[j] - mean; q += d * d; }
        #pragma unroll
        for (int m = 1; m < 16; m <<= 1) q += __shfl_xor(q, m, 64);
        float rstd = rsqrtf(q * (1.0f / 512.0f) + 1e-5f);
        u16x8 ph[4], pl[4];
        #pragma unroll
        for (int j = 0; j < 32; ++j) {
            float o = (x[j] - mean) * rstd * lg[j] + lb[j];
            unsigned short hh, ll; split2(o, hh, ll);
            ph[j >> 3][j & 7] = (unsigned short)hh;
            pl[j >> 3][j & 7] = (unsigned short)ll;
        }
        #pragma unroll
        for (int jj = 0; jj < 4; ++jj) {
            *(u16x8*)&xnH[rr][c_ * 32 + jj * 8] = ph[jj];
            *(u16x8*)&xnL[rr][c_ * 32 + jj * 8] = pl[jj];
        }
        __syncthreads();
        if (tid == 0)
            __hip_atomic_store(&cprog[cid], (unsigned)(t + 1), __ATOMIC_RELAXED, __HIP_MEMORY_SCOPE_AGENT);
        // MFMA: gx tile = xn @ wih_slice^T (+biases)
        f32x4 acc = {bias, bias, bias, bias};
        #pragma unroll
        for (int ks = 0; ks < 16; ++ks) {
            s16x8 axh = *(const s16x8*)&xnH[c_][ks * 32 + r_ * 8];
            s16x8 axl = *(const s16x8*)&xnL[c_][ks * 32 + r_ * 8];
            acc = __builtin_amdgcn_mfma_f32_16x16x32_bf16(axh, bfh[ks], acc, 0, 0, 0);
            acc = __builtin_amdgcn_mfma_f32_16x16x32_bf16(axl, bfh[ks], acc, 0, 0, 0);
            acc = __builtin_amdgcn_mfma_f32_16x16x32_bf16(axh, bfl[ks], acc, 0, 0, 0);
        }
        // gx-slot overwrite back-pressure: guards ONLY the stores below
        {
            int lim = t - 3;
            while (true) {
                int p = (int)__hip_atomic_load(&lprog[lane & 15],
                                               __ATOMIC_RELAXED, __HIP_MEMORY_SCOPE_AGENT);
                if (__all(p >= lim)) break;
                __builtin_amdgcn_s_sleep(2);
            }
        }
        float* gs = gxr + (size_t)(t & 3) * 32768;
        #pragma unroll
        for (int r = 0; r < 4; ++r)
            stf_agent(gs + (size_t)(r_ * 4 + r) * 2048 + col, acc[r]);
        asm volatile("s_waitcnt vmcnt(0)" ::: "memory");
        __syncthreads();   // all waves: gx stores drained, xn reads done
        if (tid == 0)
            __hip_atomic_store(&flags[cid], (unsigned)(t + 1), __ATOMIC_RELAXED, __HIP_MEMORY_SCOPE_AGENT);
        cph = (cph + 1 == RPH) ? 0 : cph + 1;
    }
}

__global__ __launch_bounds__(256, 1) void lstm_pipe(
        const float* __restrict__ gx0,
        const unsigned short* __restrict__ WhhH, const unsigned short* __restrict__ WhhL,
        const unsigned short* __restrict__ WihH, const unsigned short* __restrict__ WihL,
        const float* __restrict__ lng, const float* __restrict__ lnb,
        const float* __restrict__ bih, const float* __restrict__ bhh,
        float* __restrict__ hout,
        unsigned* __restrict__ rings,   // [3][RPH*8192]
        float* __restrict__ gxr,        // [2][4*32768]
        unsigned* __restrict__ ctl) {   // flag1[32] flag2[32] Lp1[16] Lp2[16] Cp1[32] Cp2[32]
    const int bid = blockIdx.x;
    const size_t WSL = (size_t)2048 * 512;
    const int RNG = RPH * 8192;
    if (bid < 16) {
        lstm_role<0>(bid, gx0, WhhH, WhhL, rings,
                     nullptr, nullptr, ctl + 96, nullptr);
    } else if (bid < 32) {
        lstm_role<1>(bid - 16, gxr, WhhH + WSL, WhhL + WSL, rings + RNG,
                     ctl + 0, ctl + 64, ctl + 128, nullptr);
    } else if (bid < 48) {
        lstm_role<1>(bid - 32, gxr + 4 * 32768, WhhH + 2 * WSL, WhhL + 2 * WSL, rings + 2 * RNG,
                     ctl + 32, ctl + 80, nullptr, hout);
    } else if (bid < 80) {
        crew_role(bid - 48, rings, gxr, ctl + 0, ctl + 96, ctl + 64,
                  WihH, WihL, lng + 512, lnb + 512, bih + 2048, bhh + 2048);
    } else {
        crew_role(bid - 80, rings + RNG, gxr + 4 * 32768, ctl + 32, ctl + 128, ctl + 80,
                  WihH + WSL, WihL + WSL, lng + 1024, lnb + 1024, bih + 4096, bhh + 4096);
    }
}

// ---------------- classifier ----------------
__global__ __launch_bounds__(256) void cls_gemm(const float* __restrict__ xn,
        const float* __restrict__ wcls, float* __restrict__ out) {
    __shared__ float wl[512][32];
    int tid = threadIdx.x;
    for (int idx = tid; idx < 512 * VO; idx += 256) {
        int k = idx / VO, v = idx - k * VO;
        wl[k][v] = wcls[idx];
    }
    __syncthreads();
    int r8 = tid >> 5, v = tid & 31;
    int row = blockIdx.x * 8 + r8;
    if (v >= VO) return;
    const float* xr = xn + (size_t)row * D_;
    float acc = 0.f;
    #pragma unroll 8
    for (int k = 0; k < 512; ++k) acc += xr[k] * wl[k][v];
    int b = row & 15, t = row >> 4;
    out[((size_t)b * T_ + t) * VO + v] = acc;
}

// ------------------------------- launch ------------------------------------------
extern "C" void kernel_launch(void* const* d_in, const int* in_sizes, int n_in,
                              void* d_out, int out_size, void* d_ws, size_t ws_size,
                              hipStream_t stream) {
    const float* x        = (const float*)d_in[0];
    const float* sru_w0   = (const float*)d_in[1];
    const float* sru_wc0  = (const float*)d_in[2];
    const float* sru_b0   = (const float*)d_in[3];
    const float* sru_ln0g = (const float*)d_in[4];
    const float* sru_ln0b = (const float*)d_in[5];
    const float* sru_w    = (const float*)d_in[6];
    const float* sru_wc   = (const float*)d_in[7];
    const float* sru_b    = (const float*)d_in[8];
    const float* sru_lng  = (const float*)d_in[9];
    const float* sru_lnb  = (const float*)d_in[10];
    const float* lstm_lng = (const float*)d_in[11];
    const float* lstm_lnb = (const float*)d_in[12];
    const float* lstm_wih = (const float*)d_in[13];
    const float* lstm_whh = (const float*)d_in[14];
    const float* lstm_bih = (const float*)d_in[15];
    const float* lstm_bhh = (const float*)d_in[16];
    const float* cls_lng  = (const float*)d_in[17];
    const float* cls_lnb  = (const float*)d_in[18];
    const float* cls_w    = (const float*)d_in[19];
    float* out = (float*)d_out;

    char* ws = (char*)d_ws;
    size_t off = 0;
    auto alloc = [&](size_t bytes) -> void* {
        off = (off + 255) & ~(size_t)255;
        void* p = ws + off;
        off += bytes;
        return p;
    };
    float* U             = (float*)alloc((size_t)M_ * 1536 * 4);
    float* hP            = (float*)alloc((size_t)M_ * D_ * 4);     // contiguous after U
    float* hQ            = (float*)alloc((size_t)M_ * D_ * 4);
    unsigned short* xnh  = (unsigned short*)alloc((size_t)M_ * D_ * 2);
    unsigned short* xnl  = (unsigned short*)alloc((size_t)M_ * D_ * 2);
    unsigned short* w0h  = (unsigned short*)alloc((size_t)2048 * 96 * 2);
    unsigned short* w0l  = (unsigned short*)alloc((size_t)2048 * 96 * 2);
    unsigned short* swh  = (unsigned short*)alloc((size_t)1536 * 512 * 2);  // SRU per-layer reuse
    unsigned short* swl  = (unsigned short*)alloc((size_t)1536 * 512 * 2);
    unsigned short* wihh = (unsigned short*)alloc((size_t)2048 * 512 * 2);  // LSTM layer-0 wih
    unsigned short* wihl = (unsigned short*)alloc((size_t)2048 * 512 * 2);
    unsigned short* whh3h = (unsigned short*)alloc((size_t)3 * 2048 * 512 * 2);
    unsigned short* whh3l = (unsigned short*)alloc((size_t)3 * 2048 * 512 * 2);
    unsigned short* wih2h = (unsigned short*)alloc((size_t)2 * 2048 * 512 * 2);
    unsigned short* wih2l = (unsigned short*)alloc((size_t)2 * 2048 * 512 * 2);
    // rings/gxr/ctl alias the SRU weight buffers (dead after SRU layers)
    unsigned* rings = (unsigned*)swh;                              // 3*RPH*8192*4 = 491.5 KB < 1.5 MB
    float*    gxr   = (float*)swl;                                 // 2*4*32768*4 = 1 MB < 1.5 MB
    unsigned* ctl   = (unsigned*)(((char*)swh) + 3 * RPH * 8192 * 4);
    float* gx = U;   // 2048-wide gx0 spans [U | hP] contiguously

    hipLaunchKernelGGL(conv_w0, dim3(768), dim3(256), 0, stream, sru_w0, w0h, w0l);

    // ---- SRU layer 0 (gx = [U|hP], output -> hQ) ----
    hipLaunchKernelGGL(ln80_kernel, dim3(4096), dim3(256), 0, stream, x, sru_ln0g, sru_ln0b, xnh, xnl);
    hipLaunchKernelGGL(gemm_split, dim3(2048 / 128, M_ / 128), dim3(256), 0, stream,
                       xnh, xnl, w0h, w0l, gx, 2048, 96, (const float*)nullptr, (const float*)nullptr);
    hipLaunchKernelGGL(sru_rec, dim3(128), dim3(64), 0, stream,
                       gx, 2048, (const float*)nullptr, sru_wc0, sru_b0, hQ);

    float* hcur = hQ; float* hnxt = hP;
    // ---- SRU layers 1..7 ----
    for (int l = 0; l < 7; ++l) {
        hipLaunchKernelGGL(conv_sruw1, dim3(3072), dim3(256), 0, stream,
                           sru_w + (size_t)l * 512 * 1536, swh, swl);
        hipLaunchKernelGGL(ln512_bf16, dim3(4096), dim3(256), 0, stream,
                           hcur, sru_lng + (size_t)l * 512, sru_lnb + (size_t)l * 512, xnh, xnl);
        hipLaunchKernelGGL(gemm_split, dim3(1536 / 128, M_ / 128), dim3(256), 0, stream,
                           xnh, xnl, swh, swl, U, 1536, 512,
                           (const float*)nullptr, (const float*)nullptr);
        hipLaunchKernelGGL(sru_rec, dim3(128), dim3(64), 0, stream,
                           U, 1536, hcur, sru_wc + (size_t)l * 1024, sru_b + (size_t)l * 1024, hnxt);
        float* tmp = hcur; hcur = hnxt; hnxt = tmp;
    }
    // after 7 layers: hcur == hP (swh/swl now dead -> alias targets)

    // ---- LSTM pre-pipe: weight splits, gx0, ring/ctl init ----
    hipLaunchKernelGGL(conv_split, dim3(12288), dim3(256), 0, stream,
                       lstm_whh, whh3h, whh3l, 3 * 2048 * 512);
    hipLaunchKernelGGL(conv_split, dim3(8192), dim3(256), 0, stream,
                       lstm_wih + (size_t)2048 * 512, wih2h, wih2l, 2 * 2048 * 512);
    hipLaunchKernelGGL(conv_split, dim3(4096), dim3(256), 0, stream,
                       lstm_wih, wihh, wihl, 2048 * 512);
    hipLaunchKernelGGL(ln512_bf16, dim3(4096), dim3(256), 0, stream,
                       hcur, lstm_lng, lstm_lnb, xnh, xnl);
    hipLaunchKernelGGL(gemm_split, dim3(2048 / 128, M_ / 128), dim3(256), 0, stream,
                       xnh, xnl, wihh, wihl, gx, 2048, 512, lstm_bih, lstm_bhh);
    hipLaunchKernelGGL(sent_fill, dim3(480), dim3(256), 0, stream, rings, 3 * RPH * 8192);
    hipLaunchKernelGGL(zero_ctl, dim3(1), dim3(256), 0, stream, ctl);

    // ---- pipelined 3-layer LSTM (one persistent kernel, 112 WGs) ----
    hipLaunchKernelGGL(lstm_pipe, dim3(112), dim3(256), 0, stream,
                       gx, whh3h, whh3l, wih2h, wih2l,
                       lstm_lng, lstm_lnb, lstm_bih, lstm_bhh,
                       hQ, rings, gxr, ctl);

    // ---- classifier ----
    hipLaunchKernelGGL(ln512_f32, dim3(4096), dim3(256), 0, stream, hQ, cls_lng, cls_lnb, (float*)U);
    hipLaunchKernelGGL(cls_gemm, dim3(2048), dim3(256), 0, stream, (const float*)U, cls_w, out);
}

// Round 13
// 8734.800 us; speedup vs baseline: 1.1183x; 1.1183x over previous
//
#include <hip/hip_runtime.h>
#include <stdint.h>
#include <stddef.h>

#define B_ 16
#define T_ 1024
#define F_ 80
#define D_ 512
#define M_ 16384   // T*B rows, row index = t*16 + b
#define VO 29      // V+1
#define SENT 0x7FC07FC0u
#define GPH 5      // gx-ring phases (sentinel-based, reset 1 ahead)

typedef float f32x4 __attribute__((ext_vector_type(4)));
typedef short s16x8 __attribute__((ext_vector_type(8)));
typedef unsigned short u16x8 __attribute__((ext_vector_type(8)));

static __device__ __forceinline__ unsigned short f2bf(float f) {
    union { float f; unsigned u; } v; v.f = f;
    unsigned r = v.u + 0x7FFFu + ((v.u >> 16) & 1u);
    return (unsigned short)(r >> 16);
}
static __device__ __forceinline__ float bf2f(unsigned short h) {
    union { unsigned u; float f; } v; v.u = ((unsigned)h) << 16; return v.f;
}
static __device__ __forceinline__ void split2(float v, unsigned short& hi, unsigned short& lo) {
    hi = f2bf(v);
    lo = f2bf(v - bf2f(hi));
}
static __device__ __forceinline__ float sigm(float x) {
    return 1.0f / (1.0f + __expf(-x));
}
static __device__ __forceinline__ float fast_tanh(float x) {
    return 1.0f - 2.0f / (__expf(2.0f * x) + 1.0f);
}
static __device__ __forceinline__ float wred(float v) {
    #pragma unroll
    for (int off = 1; off < 64; off <<= 1) v += __shfl_xor(v, off, 64);
    return v;
}
static __device__ __forceinline__ void stf_agent(float* p, float v) {
    union { float f; unsigned u; } c; c.f = v;
    __hip_atomic_store((unsigned*)p, c.u, __ATOMIC_RELAXED, __HIP_MEMORY_SCOPE_AGENT);
}
// async global->LDS, 16B per lane
static __device__ __forceinline__ void gload16(const void* g, void* lds) {
    __builtin_amdgcn_global_load_lds(
        (const __attribute__((address_space(1))) void*)g,
        (__attribute__((address_space(3))) void*)lds, 16, 0, 0);
}

// ---------------- weight conversion (fp32 -> bf16 hi/lo split) ----------------
__global__ __launch_bounds__(256) void conv_w0(const float* __restrict__ W,
        unsigned short* __restrict__ Bh, unsigned short* __restrict__ Bl) {
    int gid = blockIdx.x * 256 + threadIdx.x;     // 2048*96
    int n = gid / 96, k = gid - n * 96;
    float v = (k < 80) ? W[(size_t)k * 2048 + n] : 0.0f;
    unsigned short h, l; split2(v, h, l);
    Bh[gid] = h; Bl[gid] = l;
}
__global__ __launch_bounds__(256) void conv_sruw1(const float* __restrict__ W,
        unsigned short* __restrict__ Bh, unsigned short* __restrict__ Bl) {
    int gid = blockIdx.x * 256 + threadIdx.x;     // 1536*512
    int n = gid >> 9, k = gid & 511;
    float v = W[(size_t)k * 1536 + n];
    unsigned short h, lo; split2(v, h, lo);
    Bh[gid] = h; Bl[gid] = lo;
}
__global__ __launch_bounds__(256) void conv_split(const float* __restrict__ W,
        unsigned short* __restrict__ Oh, unsigned short* __restrict__ Ol, int n) {
    int gid = blockIdx.x * 256 + threadIdx.x;
    if (gid < n) {
        unsigned short h, l; split2(W[gid], h, l);
        Oh[gid] = h; Ol[gid] = l;
    }
}
__global__ __launch_bounds__(256) void sent_fill(unsigned int* __restrict__ buf, int n) {
    int gid = blockIdx.x * 256 + threadIdx.x;
    if (gid < n)
        __hip_atomic_store(&buf[gid], SENT, __ATOMIC_RELAXED, __HIP_MEMORY_SCOPE_AGENT);
}
__global__ void zero_ctl(unsigned int* c) {
    if (threadIdx.x < 160)
        __hip_atomic_store(&c[threadIdx.x], 0u, __ATOMIC_RELAXED, __HIP_MEMORY_SCOPE_AGENT);
}

// ---------------- LayerNorm kernels ----------------
__global__ __launch_bounds__(256) void ln80_kernel(const float* __restrict__ x,
        const float* __restrict__ g, const float* __restrict__ bta,
        unsigned short* __restrict__ xh, unsigned short* __restrict__ xl) {
    int w = threadIdx.x >> 6, lane = threadIdx.x & 63;
    int row = blockIdx.x * 4 + w;          // row = t*16 + b
    int b = row & 15, t = row >> 4;
    const float* xr = x + ((size_t)b * T_ + t) * F_;
    float v0 = xr[lane];
    float v1 = (lane < 16) ? xr[64 + lane] : 0.0f;
    float mean = wred(v0 + v1) * (1.0f / 80.0f);
    float d0 = v0 - mean;
    float d1 = (lane < 16) ? (v1 - mean) : 0.0f;
    float var = wred(d0 * d0 + d1 * d1) * (1.0f / 80.0f);
    float rstd = rsqrtf(var + 1e-5f);
    float o0 = d0 * rstd * g[lane] + bta[lane];
    unsigned short h, l; split2(o0, h, l);
    xh[(size_t)row * 96 + lane] = h;
    xl[(size_t)row * 96 + lane] = l;
    if (lane < 32) {
        unsigned short hv = 0, lv = 0;
        if (lane < 16) {
            float o1 = d1 * rstd * g[64 + lane] + bta[64 + lane];
            split2(o1, hv, lv);
        }
        xh[(size_t)row * 96 + 64 + lane] = hv;
        xl[(size_t)row * 96 + 64 + lane] = lv;
    }
}

__global__ __launch_bounds__(256) void ln512_bf16(const float* __restrict__ hsrc,
        const float* __restrict__ g, const float* __restrict__ bta,
        unsigned short* __restrict__ oh, unsigned short* __restrict__ ol) {
    int w = threadIdx.x >> 6, lane = threadIdx.x & 63;
    size_t row = (size_t)blockIdx.x * 4 + w;
    const float* hr = hsrc + row * D_;
    float4 p0 = *(const float4*)(hr + lane * 8);
    float4 p1 = *(const float4*)(hr + lane * 8 + 4);
    float s = p0.x + p0.y + p0.z + p0.w + p1.x + p1.y + p1.z + p1.w;
    float mean = wred(s) * (1.0f / 512.0f);
    float d[8] = {p0.x - mean, p0.y - mean, p0.z - mean, p0.w - mean,
                  p1.x - mean, p1.y - mean, p1.z - mean, p1.w - mean};
    float q = 0.f;
    #pragma unroll
    for (int i = 0; i < 8; ++i) q += d[i] * d[i];
    float rstd = rsqrtf(wred(q) * (1.0f / 512.0f) + 1e-5f);
    const float* gp = g + lane * 8;
    const float* bp = bta + lane * 8;
    u16x8 vh, vl;
    #pragma unroll
    for (int i = 0; i < 8; ++i) {
        float o = d[i] * rstd * gp[i] + bp[i];
        unsigned short hh, ll; split2(o, hh, ll);
        vh[i] = hh; vl[i] = ll;
    }
    *(u16x8*)(oh + row * D_ + lane * 8) = vh;
    *(u16x8*)(ol + row * D_ + lane * 8) = vl;
}

__global__ __launch_bounds__(256) void ln512_f32(const float* __restrict__ hsrc,
        const float* __restrict__ g, const float* __restrict__ bta,
        float* __restrict__ o) {
    int w = threadIdx.x >> 6, lane = threadIdx.x & 63;
    size_t row = (size_t)blockIdx.x * 4 + w;
    const float* hr = hsrc + row * D_;
    float4 p0 = *(const float4*)(hr + lane * 8);
    float4 p1 = *(const float4*)(hr + lane * 8 + 4);
    float s = p0.x + p0.y + p0.z + p0.w + p1.x + p1.y + p1.z + p1.w;
    float mean = wred(s) * (1.0f / 512.0f);
    float d[8] = {p0.x - mean, p0.y - mean, p0.z - mean, p0.w - mean,
                  p1.x - mean, p1.y - mean, p1.z - mean, p1.w - mean};
    float q = 0.f;
    #pragma unroll
    for (int i = 0; i < 8; ++i) q += d[i] * d[i];
    float rstd = rsqrtf(wred(q) * (1.0f / 512.0f) + 1e-5f);
    const float* gp = g + lane * 8;
    const float* bp = bta + lane * 8;
    float* op = o + row * D_ + lane * 8;
    #pragma unroll
    for (int i = 0; i < 8; ++i) op[i] = d[i] * rstd * gp[i] + bp[i];
}

// ------- split bf16 MFMA GEMM, 128x128 tile, global_load_lds + XOR swizzle -------
__global__ __launch_bounds__(256) void gemm_split(
        const unsigned short* __restrict__ Ah, const unsigned short* __restrict__ Al,
        const unsigned short* __restrict__ Bh, const unsigned short* __restrict__ Bl,
        float* __restrict__ C, int N, int Kp,
        const float* __restrict__ bias0, const float* __restrict__ bias1) {
    __shared__ __align__(16) unsigned short sAh[4096];
    __shared__ __align__(16) unsigned short sAl[4096];
    __shared__ __align__(16) unsigned short sBh[4096];
    __shared__ __align__(16) unsigned short sBl[4096];
    const int tid = threadIdx.x;
    const int wv = tid >> 6, lane = tid & 63;
    const int c_ = lane & 15, r_ = lane >> 4;
    const int wr = wv >> 1, wc = wv & 1;
    const int mBase = blockIdx.y * 128, nBase = blockIdx.x * 128;

    const int row0 = tid >> 2, row1 = 64 + row0;
    const int sp = tid & 3;
    const int x0 = (row0 & 3) ^ ((row0 >> 2) & 3);
    const int x1 = (row1 & 3) ^ ((row1 >> 2) & 3);
    const size_t gA0 = (size_t)(mBase + row0) * Kp + (size_t)((sp ^ x0) * 8);
    const size_t gA1 = (size_t)(mBase + row1) * Kp + (size_t)((sp ^ x1) * 8);
    const size_t gB0 = (size_t)(nBase + row0) * Kp + (size_t)((sp ^ x0) * 8);
    const size_t gB1 = (size_t)(nBase + row1) * Kp + (size_t)((sp ^ x1) * 8);
    const int ldsW = wv * 1024;

    int offA[4], offB[4];
    #pragma unroll
    for (int f = 0; f < 4; ++f) {
        int ra = wr * 64 + f * 16 + c_;
        int xa = (ra & 3) ^ ((ra >> 2) & 3);
        offA[f] = ra * 32 + ((r_ ^ xa) * 8);
        int rb = wc * 64 + f * 16 + c_;
        int xb = (rb & 3) ^ ((rb >> 2) & 3);
        offB[f] = rb * 32 + ((r_ ^ xb) * 8);
    }

    f32x4 acc[4][4] = {};
    for (int kt = 0; kt < Kp; kt += 32) {
        gload16(Ah + gA0 + kt, (char*)sAh + ldsW);
        gload16(Ah + gA1 + kt, (char*)sAh + 4096 + ldsW);
        gload16(Al + gA0 + kt, (char*)sAl + ldsW);
        gload16(Al + gA1 + kt, (char*)sAl + 4096 + ldsW);
        gload16(Bh + gB0 + kt, (char*)sBh + ldsW);
        gload16(Bh + gB1 + kt, (char*)sBh + 4096 + ldsW);
        gload16(Bl + gB0 + kt, (char*)sBl + ldsW);
        gload16(Bl + gB1 + kt, (char*)sBl + 4096 + ldsW);
        __syncthreads();
        s16x8 ah[4], al[4], bh[4], bl[4];
        #pragma unroll
        for (int f = 0; f < 4; ++f) {
            ah[f] = *(const s16x8*)&sAh[offA[f]];
            al[f] = *(const s16x8*)&sAl[offA[f]];
            bh[f] = *(const s16x8*)&sBh[offB[f]];
            bl[f] = *(const s16x8*)&sBl[offB[f]];
        }
        #pragma unroll
        for (int mf = 0; mf < 4; ++mf) {
            #pragma unroll
            for (int nf = 0; nf < 4; ++nf) {
                acc[mf][nf] = __builtin_amdgcn_mfma_f32_16x16x32_bf16(ah[mf], bh[nf], acc[mf][nf], 0, 0, 0);
                acc[mf][nf] = __builtin_amdgcn_mfma_f32_16x16x32_bf16(al[mf], bh[nf], acc[mf][nf], 0, 0, 0);
                acc[mf][nf] = __builtin_amdgcn_mfma_f32_16x16x32_bf16(ah[mf], bl[nf], acc[mf][nf], 0, 0, 0);
            }
        }
        __syncthreads();
    }
    #pragma unroll
    for (int mf = 0; mf < 4; ++mf) {
        #pragma unroll
        for (int r = 0; r < 4; ++r) {
            int m = mBase + wr * 64 + mf * 16 + r_ * 4 + r;
            float* crow = C + (size_t)m * N + nBase + wc * 64;
            #pragma unroll
            for (int nf = 0; nf < 4; ++nf) {
                int n = nBase + wc * 64 + nf * 16 + c_;
                float v = acc[mf][nf][r];
                if (bias0) v += bias0[n];
                if (bias1) v += bias1[n];
                crow[nf * 16 + c_] = v;
            }
        }
    }
}

// ---------------- SRU recurrence ----------------
__global__ __launch_bounds__(64) void sru_rec(const float* __restrict__ U, int NU,
        const float* __restrict__ xprev, const float* __restrict__ wc,
        const float* __restrict__ bias, float* __restrict__ hout) {
    int gid = blockIdx.x * 64 + threadIdx.x;
    int d = gid & (D_ - 1), b = gid >> 9;
    float vf = wc[d], vr = wc[D_ + d];
    float bf = bias[d], br = bias[D_ + d];
    const float* u0 = U + d;
    const float* u1 = U + D_ + d;
    const float* u2 = U + 2 * D_ + d;
    const float* xr;  size_t xstride;
    if (xprev) { xr = xprev + d; xstride = D_; }
    else       { xr = U + 3 * (size_t)D_ + d; xstride = (size_t)NU; }
    float* ho = hout + d;
    float c = 0.f;
    #pragma unroll 4
    for (int t = 0; t < T_; ++t) {
        size_t row = (size_t)(t * 16 + b);
        float a0 = u0[row * NU];
        float a1 = u1[row * NU];
        float a2 = u2[row * NU];
        float xv = xr[row * xstride];
        float f = sigm(a1 + vf * c + bf);
        float r = sigm(a2 + vr * c + br);
        c = f * c + (1.f - f) * a0;
        float h = r * c + (1.f - r) * xv;
        ho[row * D_] = h;
    }
}

// =================== 3-layer pipelined LSTM (persistent, 112 WGs) ===================
// Roles: [0,16) LSTM L0 | [16,32) L1 | [32,48) L2 | [48,80) crew1 | [80,112) crew2.
// h-rings: 3-phase sentinel rings (round-11 proven). CHANGE (r13): gx exchange is
// ALSO a NaN-sentinel ring (5 slots): crew drops its post-store drain + flag
// (~1-1.5us off the crew stage period); L sentinel-polls gx in the prefetch slot.
// Finite fp32 never has upper-16 == 0x7FC0 (would need exponent 0xFF) -> safe.

template <int MODE>
static __device__ void lstm_role(int wg, const float* gxsrc,
        const unsigned short* Wh, const unsigned short* Wl,
        unsigned* ring, unsigned* myLprog,
        const unsigned* consCprog, float* hout) {
    __shared__ __align__(16) unsigned short hH[16][520];
    __shared__ __align__(16) unsigned short hL[16][520];
    __shared__ float G[16][132];
    const int tid = threadIdx.x;
    const int w = tid >> 6, lane = tid & 63;
    const int c_ = lane & 15, r_ = lane >> 4;

    s16x8 bh0[16], bh1[16], bl0[16], bl1[16];
    {
        size_t R0 = (size_t)(w * 512 + wg * 32 + c_) * 512;
        size_t R1 = R0 + 16 * 512;
        #pragma unroll
        for (int ks = 0; ks < 16; ++ks) {
            bh0[ks] = *(const s16x8*)(Wh + R0 + ks * 32 + r_ * 8);
            bh1[ks] = *(const s16x8*)(Wh + R1 + ks * 32 + r_ * 8);
            bl0[ks] = *(const s16x8*)(Wl + R0 + ks * 32 + r_ * 8);
            bl1[ks] = *(const s16x8*)(Wl + R1 + ks * 32 + r_ * 8);
        }
    }
    for (int i = tid; i < 16 * 520; i += 256) {
        ((unsigned short*)hH)[i] = 0;
        ((unsigned short*)hL)[i] = 0;
    }
    const int eb = tid >> 4;
    const int ed = (tid * 2) & 31;
    float cc0 = 0.f, cc1 = 0.f;
    const int col0 = w * 512 + wg * 32 + c_;
    const int hidx = (eb * 512 + wg * 32 + ed) >> 1;

    float gxv0[4], gxv1[4];
    if (MODE == 0) {
        #pragma unroll
        for (int r = 0; r < 4; ++r) {
            int bt = r_ * 4 + r;
            gxv0[r] = gxsrc[(size_t)bt * 2048 + col0];
            gxv1[r] = gxsrc[(size_t)bt * 2048 + col0 + 16];
        }
    } else {
        // initial fetch of gx_0: sentinel poll of slot 0
        const float* gs = gxsrc;
        unsigned gv[8];
        unsigned gb = 0xFFu;
        while (true) {
            #pragma unroll
            for (int r = 0; r < 4; ++r) {
                int bt = r_ * 4 + r;
                if (gb & (1u << r))
                    gv[r] = __hip_atomic_load((const unsigned*)(gs + (size_t)bt * 2048 + col0),
                                              __ATOMIC_RELAXED, __HIP_MEMORY_SCOPE_AGENT);
                if (gb & (1u << (4 + r)))
                    gv[4 + r] = __hip_atomic_load((const unsigned*)(gs + (size_t)bt * 2048 + col0 + 16),
                                                  __ATOMIC_RELAXED, __HIP_MEMORY_SCOPE_AGENT);
            }
            unsigned nb = 0u;
            #pragma unroll
            for (int r = 0; r < 8; ++r)
                if ((gv[r] >> 16) == 0x7FC0u) nb |= 1u << r;
            gb = nb;
            if (!__any(gb != 0u)) break;
            __builtin_amdgcn_s_sleep(1);
        }
        #pragma unroll
        for (int r = 0; r < 4; ++r) {
            union { unsigned u; float f; } c0, c1;
            c0.u = gv[r]; c1.u = gv[4 + r];
            gxv0[r] = c0.f; gxv1[r] = c1.f;
        }
    }
    int pcur = 0, pnxt = 8192, pthr = 16384;
    __syncthreads();

    for (int t = 0; t < T_; ++t) {
        if (MODE == 1 && tid == 0)
            __hip_atomic_store(&myLprog[wg], (unsigned)t, __ATOMIC_RELAXED, __HIP_MEMORY_SCOPE_AGENT);
        // crew-ack gate: crew must have consumed h_{t-2} before we reset its slot
        if (consCprog) {
            int lim = t - 1;
            while (true) {
                int p = (int)__hip_atomic_load(&consCprog[lane & 31],
                                               __ATOMIC_RELAXED, __HIP_MEMORY_SCOPE_AGENT);
                if (__all(p >= lim)) break;
                __builtin_amdgcn_s_sleep(2);
            }
        }
        __hip_atomic_store(&ring[pnxt + hidx], SENT, __ATOMIC_RELAXED, __HIP_MEMORY_SCOPE_AGENT);
        __hip_atomic_store(&ring[pnxt + 4096 + hidx], SENT, __ATOMIC_RELAXED, __HIP_MEMORY_SCOPE_AGENT);
        f32x4 acc0 = {0.f, 0.f, 0.f, 0.f};
        f32x4 acc1 = {0.f, 0.f, 0.f, 0.f};
        #pragma unroll
        for (int ks = 0; ks < 16; ++ks) {
            s16x8 ah = *(const s16x8*)&hH[c_][ks * 32 + r_ * 8];
            s16x8 al = *(const s16x8*)&hL[c_][ks * 32 + r_ * 8];
            acc0 = __builtin_amdgcn_mfma_f32_16x16x32_bf16(ah, bh0[ks], acc0, 0, 0, 0);
            acc1 = __builtin_amdgcn_mfma_f32_16x16x32_bf16(ah, bh1[ks], acc1, 0, 0, 0);
            acc0 = __builtin_amdgcn_mfma_f32_16x16x32_bf16(al, bh0[ks], acc0, 0, 0, 0);
            acc1 = __builtin_amdgcn_mfma_f32_16x16x32_bf16(al, bh1[ks], acc1, 0, 0, 0);
            acc0 = __builtin_amdgcn_mfma_f32_16x16x32_bf16(ah, bl0[ks], acc0, 0, 0, 0);
            acc1 = __builtin_amdgcn_mfma_f32_16x16x32_bf16(ah, bl1[ks], acc1, 0, 0, 0);
        }
        #pragma unroll
        for (int r = 0; r < 4; ++r) {
            int bt = r_ * 4 + r;
            G[bt][w * 32 + c_]      = acc0[r] + gxv0[r];
            G[bt][w * 32 + 16 + c_] = acc1[r] + gxv1[r];
        }
        __syncthreads();
        float iv0 = G[eb][ed],     fv0 = G[eb][32 + ed], gv0 = G[eb][64 + ed], ov0 = G[eb][96 + ed];
        float iv1 = G[eb][ed + 1], fv1 = G[eb][33 + ed], gv1 = G[eb][65 + ed], ov1 = G[eb][97 + ed];
        cc0 = sigm(fv0) * cc0 + sigm(iv0) * fast_tanh(gv0);
        cc1 = sigm(fv1) * cc1 + sigm(iv1) * fast_tanh(gv1);
        float h0 = sigm(ov0) * fast_tanh(cc0);
        float h1 = sigm(ov1) * fast_tanh(cc1);
        asm volatile("s_waitcnt vmcnt(0)" ::: "memory");
        unsigned short h0h, h0l, h1h, h1l;
        split2(h0, h0h, h0l); split2(h1, h1h, h1l);
        unsigned packH = (unsigned)h0h | ((unsigned)h1h << 16);
        unsigned packL = (unsigned)h0l | ((unsigned)h1l << 16);
        __hip_atomic_store(&ring[pcur + hidx], packH, __ATOMIC_RELAXED, __HIP_MEMORY_SCOPE_AGENT);
        __hip_atomic_store(&ring[pcur + 4096 + hidx], packL, __ATOMIC_RELAXED, __HIP_MEMORY_SCOPE_AGENT);
        if (hout) {
            size_t orow = (size_t)(t * 16 + eb) * D_ + wg * 32 + ed;
            hout[orow] = h0; hout[orow + 1] = h1;
        }
        if (t == T_ - 1) break;
        // prefetch gx_{t+1} (cached for MODE 0; sentinel-poll of gx-ring for MODE 1,
        // overlapped with the h-ring poll below)
        if (MODE == 0) {
            const float* gxr = gxsrc + (size_t)((t + 1) * 16) * 2048;
            #pragma unroll
            for (int r = 0; r < 4; ++r) {
                int bt = r_ * 4 + r;
                gxv0[r] = gxr[(size_t)bt * 2048 + col0];
                gxv1[r] = gxr[(size_t)bt * 2048 + col0 + 16];
            }
        } else {
            const float* gs = gxsrc + (size_t)((t + 1) % GPH) * 32768;
            unsigned gv[8];
            unsigned gb = 0xFFu;
            while (true) {
                #pragma unroll
                for (int r = 0; r < 4; ++r) {
                    int bt = r_ * 4 + r;
                    if (gb & (1u << r))
                        gv[r] = __hip_atomic_load((const unsigned*)(gs + (size_t)bt * 2048 + col0),
                                                  __ATOMIC_RELAXED, __HIP_MEMORY_SCOPE_AGENT);
                    if (gb & (1u << (4 + r)))
                        gv[4 + r] = __hip_atomic_load((const unsigned*)(gs + (size_t)bt * 2048 + col0 + 16),
                                                      __ATOMIC_RELAXED, __HIP_MEMORY_SCOPE_AGENT);
                }
                unsigned nb = 0u;
                #pragma unroll
                for (int r = 0; r < 8; ++r)
                    if ((gv[r] >> 16) == 0x7FC0u) nb |= 1u << r;
                gb = nb;
                if (!__any(gb != 0u)) break;
                __builtin_amdgcn_s_sleep(1);
            }
            #pragma unroll
            for (int r = 0; r < 4; ++r) {
                union { unsigned u; float f; } c0, c1;
                c0.u = gv[r]; c1.u = gv[4 + r];
                gxv0[r] = c0.f; gxv1[r] = c1.f;
            }
        }
        // ---- h-ring sentinel poll with repair re-reads ----
        unsigned long long vh[8], vl[8];
        unsigned badm = 0xFFFFu;
        while (true) {
            #pragma unroll
            for (int j = 0; j < 8; ++j) {
                int q = pcur + j * 512 + tid * 2;
                if (badm & (1u << j))
                    vh[j] = __hip_atomic_load((const unsigned long long*)&ring[q],
                                              __ATOMIC_RELAXED, __HIP_MEMORY_SCOPE_AGENT);
                if (badm & (1u << (8 + j)))
                    vl[j] = __hip_atomic_load((const unsigned long long*)&ring[q + 4096],
                                              __ATOMIC_RELAXED, __HIP_MEMORY_SCOPE_AGENT);
            }
            unsigned nb = 0u;
            #pragma unroll
            for (int j = 0; j < 8; ++j) {
                unsigned a0 = (unsigned)vh[j], a1 = (unsigned)(vh[j] >> 32);
                unsigned b0 = (unsigned)vl[j], b1 = (unsigned)(vl[j] >> 32);
                if (((a0 >> 16) == 0x7FC0u) || ((a1 >> 16) == 0x7FC0u)) nb |= 1u << j;
                if (((b0 >> 16) == 0x7FC0u) || ((b1 >> 16) == 0x7FC0u)) nb |= 1u << (8 + j);
            }
            badm = nb;
            if (!__any(badm != 0u)) break;
            __builtin_amdgcn_s_sleep(1);
        }
        #pragma unroll
        for (int j = 0; j < 8; ++j) {
            int q = j * 512 + tid * 2;
            int bb = q >> 8, dd = (q & 255) * 2;
            *(unsigned long long*)&hH[bb][dd] = vh[j];
            *(unsigned long long*)&hL[bb][dd] = vl[j];
        }
        __syncthreads();
        int tmp = pcur; pcur = pnxt; pnxt = pthr; pthr = tmp;
    }
}

// crew: per step, LN(h^l_t) then gx^{l+1}_t tile (64 cols) via 3-term MFMA.
// gx published via sentinel ring: reset slot (t+1)%GPH at top (gated), drain
// BEFORE data stores (orders resets-before-data), no flag, no post-drain.
static __device__ void crew_role(int cid, const unsigned* srcring, float* gxr,
        unsigned* cprog, const unsigned* lprog,
        const unsigned short* WihHp, const unsigned short* WihLp,
        const float* g, const float* bta,
        const float* bihp, const float* bhhp) {
    __shared__ __align__(16) unsigned short xnH[16][520];
    __shared__ __align__(16) unsigned short xnL[16][520];
    const int tid = threadIdx.x;
    const int w = tid >> 6, lane = tid & 63;
    const int c_ = lane & 15, r_ = lane >> 4;
    const int col = cid * 64 + w * 16 + c_;
    const int rr = w * 4 + r_;          // LN row owned by this lane

    s16x8 bfh[16], bfl[16];
    {
        const unsigned short* wrH = WihHp + (size_t)col * 512;
        const unsigned short* wrL = WihLp + (size_t)col * 512;
        #pragma unroll
        for (int ks = 0; ks < 16; ++ks) {
            bfh[ks] = *(const s16x8*)(wrH + ks * 32 + r_ * 8);
            bfl[ks] = *(const s16x8*)(wrL + ks * 32 + r_ * 8);
        }
    }
    const float bias = bihp[col] + bhhp[col];
    float lg[32], lb[32];
    #pragma unroll
    for (int j = 0; j < 32; ++j) { lg[j] = g[c_ * 32 + j]; lb[j] = bta[c_ * 32 + j]; }

    for (int t = 0; t < T_; ++t) {
        // gx-ring gate: guards the reset of slot (t+1)%GPH (holds gx_{t+1-GPH})
        // and the stores to slot t%GPH. L prefetches gx_k at its step k-1.
        {
            int lim = t - 3;
            while (true) {
                int p = (int)__hip_atomic_load(&lprog[lane & 15],
                                               __ATOMIC_RELAXED, __HIP_MEMORY_SCOPE_AGENT);
                if (__all(p >= lim)) break;
                __builtin_amdgcn_s_sleep(2);
            }
        }
        // reset own words of slot (t+1)%GPH (drained before this step's data stores)
        {
            unsigned* rs = (unsigned*)(gxr + (size_t)((t + 1) % GPH) * 32768);
            #pragma unroll
            for (int r = 0; r < 4; ++r)
                __hip_atomic_store(&rs[(size_t)(r_ * 4 + r) * 2048 + col], SENT,
                                   __ATOMIC_RELAXED, __HIP_MEMORY_SCOPE_AGENT);
        }
        // sentinel-poll h^l_t (own LN window) with repair re-reads
        const unsigned* sb = srcring + (t % 3) * 8192;
        const int qi = rr * 256 + c_ * 16;
        unsigned long long vh[8], vl[8];
        unsigned badm = 0xFFFFu;
        while (true) {
            #pragma unroll
            for (int j = 0; j < 8; ++j) {
                if (badm & (1u << j))
                    vh[j] = __hip_atomic_load((const unsigned long long*)&sb[qi + j * 2],
                                              __ATOMIC_RELAXED, __HIP_MEMORY_SCOPE_AGENT);
                if (badm & (1u << (8 + j)))
                    vl[j] = __hip_atomic_load((const unsigned long long*)&sb[4096 + qi + j * 2],
                                              __ATOMIC_RELAXED, __HIP_MEMORY_SCOPE_AGENT);
            }
            unsigned nb = 0u;
            #pragma unroll
            for (int j = 0; j < 8; ++j) {
                unsigned a0 = (unsigned)vh[j], a1 = (unsigned)(vh[j] >> 32);
                unsigned b0 = (unsigned)vl[j], b1 = (unsigned)(vl[j] >> 32);
                if (((a0 >> 16) == 0x7FC0u) || ((a1 >> 16) == 0x7FC0u)) nb |= 1u << j;
                if (((b0 >> 16) == 0x7FC0u) || ((b1 >> 16) == 0x7FC0u)) nb |= 1u << (8 + j);
            }
            badm = nb;
            if (!__any(badm != 0u)) break;
            __builtin_amdgcn_s_sleep(1);
        }
        // reconstruct 32 fp32 values
        float x[32];
        #pragma unroll
        for (int k = 0; k < 8; ++k) {
            unsigned ah = (unsigned)vh[k], bh = (unsigned)(vh[k] >> 32);
            unsigned al = (unsigned)vl[k], bl = (unsigned)(vl[k] >> 32);
            x[4 * k + 0] = bf2f((unsigned short)ah) + bf2f((unsigned short)al);
            x[4 * k + 1] = bf2f((unsigned short)(ah >> 16)) + bf2f((unsigned short)(al >> 16));
            x[4 * k + 2] = bf2f((unsigned short)bh) + bf2f((unsigned short)bl);
            x[4 * k + 3] = bf2f((unsigned short)(bh >> 16)) + bf2f((unsigned short)(bl >> 16));
        }
        // LN across the 16-lane row group
        float s = 0.f;
        #pragma unroll
        for (int j = 0; j < 32; ++j) s += x[j];
        #pragma unroll
        for (int m = 1; m < 16; m <<= 1) s += __shfl_xor(s, m, 64);
        float mean = s * (1.0f / 512.0f);
        float q = 0.f;
        #pragma unroll
        for (int j = 0; j < 32; ++j) { float d = x[j] - mean; q += d * d; }
        #pragma unroll
        for (int m = 1; m < 16; m <<= 1) q += __shfl_xor(q, m, 64);
        float rstd = rsqrtf(q * (1.0f / 512.0f) + 1e-5f);
        u16x8 ph[4], pl[4];
        #pragma unroll
        for (int j = 0; j < 32; ++j) {
            float o = (x[j] - mean) * rstd * lg[j] + lb[j];
            unsigned short hh, ll; split2(o, hh, ll);
            ph[j >> 3][j & 7] = (unsigned short)hh;
            pl[j >> 3][j & 7] = (unsigned short)ll;
        }
        #pragma unroll
        for (int jj = 0; jj < 4; ++jj) {
            *(u16x8*)&xnH[rr][c_ * 32 + jj * 8] = ph[jj];
            *(u16x8*)&xnL[rr][c_ * 32 + jj * 8] = pl[jj];
        }
        __syncthreads();
        if (tid == 0)
            __hip_atomic_store(&cprog[cid], (unsigned)(t + 1), __ATOMIC_RELAXED, __HIP_MEMORY_SCOPE_AGENT);
        // MFMA: gx tile = xn @ wih_slice^T (+biases)
        f32x4 acc = {bias, bias, bias, bias};
        #pragma unroll
        for (int ks = 0; ks < 16; ++ks) {
            s16x8 axh = *(const s16x8*)&xnH[c_][ks * 32 + r_ * 8];
            s16x8 axl = *(const s16x8*)&xnL[c_][ks * 32 + r_ * 8];
            acc = __builtin_amdgcn_mfma_f32_16x16x32_bf16(axh, bfh[ks], acc, 0, 0, 0);
            acc = __builtin_amdgcn_mfma_f32_16x16x32_bf16(axl, bfh[ks], acc, 0, 0, 0);
            acc = __builtin_amdgcn_mfma_f32_16x16x32_bf16(axh, bfl[ks], acc, 0, 0, 0);
        }
        // drain BEFORE data stores: resets (and all prior ops) visible first;
        // consumers then detect gx arrival via the data itself (no flag needed)
        asm volatile("s_waitcnt vmcnt(0)" ::: "memory");
        float* gs = gxr + (size_t)(t % GPH) * 32768;
        #pragma unroll
        for (int r = 0; r < 4; ++r)
            stf_agent(gs + (size_t)(r_ * 4 + r) * 2048 + col, acc[r]);
        __syncthreads();   // xn reads done before next step's writes
    }
}

__global__ __launch_bounds__(256, 1) void lstm_pipe(
        const float* __restrict__ gx0,
        const unsigned short* __restrict__ WhhH, const unsigned short* __restrict__ WhhL,
        const unsigned short* __restrict__ WihH, const unsigned short* __restrict__ WihL,
        const float* __restrict__ lng, const float* __restrict__ lnb,
        const float* __restrict__ bih, const float* __restrict__ bhh,
        float* __restrict__ hout,
        unsigned* __restrict__ rings,   // [3][3*8192]
        float* __restrict__ gxr,        // [2][GPH*32768]
        unsigned* __restrict__ ctl) {   // [0..63] unused, Lp1[16]@64, Lp2[16]@80, Cp1[32]@96, Cp2[32]@128
    const int bid = blockIdx.x;
    const size_t WSL = (size_t)2048 * 512;
    const int RNG = 3 * 8192;
    if (bid < 16) {
        lstm_role<0>(bid, gx0, WhhH, WhhL, rings,
                     nullptr, ctl + 96, nullptr);
    } else if (bid < 32) {
        lstm_role<1>(bid - 16, gxr, WhhH + WSL, WhhL + WSL, rings + RNG,
                     ctl + 64, ctl + 128, nullptr);
    } else if (bid < 48) {
        lstm_role<1>(bid - 32, gxr + (size_t)GPH * 32768, WhhH + 2 * WSL, WhhL + 2 * WSL,
                     rings + 2 * RNG, ctl + 80, nullptr, hout);
    } else if (bid < 80) {
        crew_role(bid - 48, rings, gxr, ctl + 96, ctl + 64,
                  WihH, WihL, lng + 512, lnb + 512, bih + 2048, bhh + 2048);
    } else {
        crew_role(bid - 80, rings + RNG, gxr + (size_t)GPH * 32768, ctl + 128, ctl + 80,
                  WihH + WSL, WihL + WSL, lng + 1024, lnb + 1024, bih + 4096, bhh + 4096);
    }
}

// ---------------- classifier ----------------
__global__ __launch_bounds__(256) void cls_gemm(const float* __restrict__ xn,
        const float* __restrict__ wcls, float* __restrict__ out) {
    __shared__ float wl[512][32];
    int tid = threadIdx.x;
    for (int idx = tid; idx < 512 * VO; idx += 256) {
        int k = idx / VO, v = idx - k * VO;
        wl[k][v] = wcls[idx];
    }
    __syncthreads();
    int r8 = tid >> 5, v = tid & 31;
    int row = blockIdx.x * 8 + r8;
    if (v >= VO) return;
    const float* xr = xn + (size_t)row * D_;
    float acc = 0.f;
    #pragma unroll 8
    for (int k = 0; k < 512; ++k) acc += xr[k] * wl[k][v];
    int b = row & 15, t = row >> 4;
    out[((size_t)b * T_ + t) * VO + v] = acc;
}

// ------------------------------- launch ------------------------------------------
extern "C" void kernel_launch(void* const* d_in, const int* in_sizes, int n_in,
                              void* d_out, int out_size, void* d_ws, size_t ws_size,
                              hipStream_t stream) {
    const float* x        = (const float*)d_in[0];
    const float* sru_w0   = (const float*)d_in[1];
    const float* sru_wc0  = (const float*)d_in[2];
    const float* sru_b0   = (const float*)d_in[3];
    const float* sru_ln0g = (const float*)d_in[4];
    const float* sru_ln0b = (const float*)d_in[5];
    const float* sru_w    = (const float*)d_in[6];
    const float* sru_wc   = (const float*)d_in[7];
    const float* sru_b    = (const float*)d_in[8];
    const float* sru_lng  = (const float*)d_in[9];
    const float* sru_lnb  = (const float*)d_in[10];
    const float* lstm_lng = (const float*)d_in[11];
    const float* lstm_lnb = (const float*)d_in[12];
    const float* lstm_wih = (const float*)d_in[13];
    const float* lstm_whh = (const float*)d_in[14];
    const float* lstm_bih = (const float*)d_in[15];
    const float* lstm_bhh = (const float*)d_in[16];
    const float* cls_lng  = (const float*)d_in[17];
    const float* cls_lnb  = (const float*)d_in[18];
    const float* cls_w    = (const float*)d_in[19];
    float* out = (float*)d_out;

    char* ws = (char*)d_ws;
    size_t off = 0;
    auto alloc = [&](size_t bytes) -> void* {
        off = (off + 255) & ~(size_t)255;
        void* p = ws + off;
        off += bytes;
        return p;
    };
    float* U             = (float*)alloc((size_t)M_ * 1536 * 4);
    float* hP            = (float*)alloc((size_t)M_ * D_ * 4);     // contiguous after U
    float* hQ            = (float*)alloc((size_t)M_ * D_ * 4);
    unsigned short* xnh  = (unsigned short*)alloc((size_t)M_ * D_ * 2);
    unsigned short* xnl  = (unsigned short*)alloc((size_t)M_ * D_ * 2);
    unsigned short* w0h  = (unsigned short*)alloc((size_t)2048 * 96 * 2);
    unsigned short* w0l  = (unsigned short*)alloc((size_t)2048 * 96 * 2);
    unsigned short* swh  = (unsigned short*)alloc((size_t)1536 * 512 * 2);  // SRU per-layer reuse
    unsigned short* swl  = (unsigned short*)alloc((size_t)1536 * 512 * 2);
    unsigned short* wihh = (unsigned short*)alloc((size_t)2048 * 512 * 2);  // LSTM layer-0 wih
    unsigned short* wihl = (unsigned short*)alloc((size_t)2048 * 512 * 2);
    unsigned short* whh3h = (unsigned short*)alloc((size_t)3 * 2048 * 512 * 2);
    unsigned short* whh3l = (unsigned short*)alloc((size_t)3 * 2048 * 512 * 2);
    unsigned short* wih2h = (unsigned short*)alloc((size_t)2 * 2048 * 512 * 2);
    unsigned short* wih2l = (unsigned short*)alloc((size_t)2 * 2048 * 512 * 2);
    // rings/gxr/ctl alias the SRU weight buffers (dead after SRU layers)
    unsigned* rings = (unsigned*)swh;                              // 3*3*8192*4 = 288 KB < 1.5 MB
    float*    gxr   = (float*)swl;                                 // 2*GPH*32768*4 = 1.25 MB < 1.5 MB
    unsigned* ctl   = (unsigned*)(((char*)swh) + 3 * 3 * 8192 * 4);
    float* gx = U;   // 2048-wide gx0 spans [U | hP] contiguously

    hipLaunchKernelGGL(conv_w0, dim3(768), dim3(256), 0, stream, sru_w0, w0h, w0l);

    // ---- SRU layer 0 (gx = [U|hP], output -> hQ) ----
    hipLaunchKernelGGL(ln80_kernel, dim3(4096), dim3(256), 0, stream, x, sru_ln0g, sru_ln0b, xnh, xnl);
    hipLaunchKernelGGL(gemm_split, dim3(2048 / 128, M_ / 128), dim3(256), 0, stream,
                       xnh, xnl, w0h, w0l, gx, 2048, 96, (const float*)nullptr, (const float*)nullptr);
    hipLaunchKernelGGL(sru_rec, dim3(128), dim3(64), 0, stream,
                       gx, 2048, (const float*)nullptr, sru_wc0, sru_b0, hQ);

    float* hcur = hQ; float* hnxt = hP;
    // ---- SRU layers 1..7 ----
    for (int l = 0; l < 7; ++l) {
        hipLaunchKernelGGL(conv_sruw1, dim3(3072), dim3(256), 0, stream,
                           sru_w + (size_t)l * 512 * 1536, swh, swl);
        hipLaunchKernelGGL(ln512_bf16, dim3(4096), dim3(256), 0, stream,
                           hcur, sru_lng + (size_t)l * 512, sru_lnb + (size_t)l * 512, xnh, xnl);
        hipLaunchKernelGGL(gemm_split, dim3(1536 / 128, M_ / 128), dim3(256), 0, stream,
                           xnh, xnl, swh, swl, U, 1536, 512,
                           (const float*)nullptr, (const float*)nullptr);
        hipLaunchKernelGGL(sru_rec, dim3(128), dim3(64), 0, stream,
                           U, 1536, hcur, sru_wc + (size_t)l * 1024, sru_b + (size_t)l * 1024, hnxt);
        float* tmp = hcur; hcur = hnxt; hnxt = tmp;
    }
    // after 7 layers: hcur == hP (swh/swl now dead -> alias targets)

    // ---- LSTM pre-pipe: weight splits, gx0, ring/ctl init ----
    hipLaunchKernelGGL(conv_split, dim3(12288), dim3(256), 0, stream,
                       lstm_whh, whh3h, whh3l, 3 * 2048 * 512);
    hipLaunchKernelGGL(conv_split, dim3(8192), dim3(256), 0, stream,
                       lstm_wih + (size_t)2048 * 512, wih2h, wih2l, 2 * 2048 * 512);
    hipLaunchKernelGGL(conv_split, dim3(4096), dim3(256), 0, stream,
                       lstm_wih, wihh, wihl, 2048 * 512);
    hipLaunchKernelGGL(ln512_bf16, dim3(4096), dim3(256), 0, stream,
                       hcur, lstm_lng, lstm_lnb, xnh, xnl);
    hipLaunchKernelGGL(gemm_split, dim3(2048 / 128, M_ / 128), dim3(256), 0, stream,
                       xnh, xnl, wihh, wihl, gx, 2048, 512, lstm_bih, lstm_bhh);
    hipLaunchKernelGGL(sent_fill, dim3(288), dim3(256), 0, stream, rings, 3 * 3 * 8192);
    hipLaunchKernelGGL(sent_fill, dim3(1280), dim3(256), 0, stream, (unsigned*)gxr, 2 * GPH * 32768);
    hipLaunchKernelGGL(zero_ctl, dim3(1), dim3(256), 0, stream, ctl);

    // ---- pipelined 3-layer LSTM (one persistent kernel, 112 WGs) ----
    hipLaunchKernelGGL(lstm_pipe, dim3(112), dim3(256), 0, stream,
                       gx, whh3h, whh3l, wih2h, wih2l,
                       lstm_lng, lstm_lnb, lstm_bih, lstm_bhh,
                       hQ, rings, gxr, ctl);

    // ---- classifier ----
    hipLaunchKernelGGL(ln512_f32, dim3(4096), dim3(256), 0, stream, hQ, cls_lng, cls_lnb, (float*)U);
    hipLaunchKernelGGL(cls_gemm, dim3(2048), dim3(256), 0, stream, (const float*)U, cls_w, out);
}

// Round 14
// 7998.914 us; speedup vs baseline: 1.2211x; 1.0920x over previous
//
#include <hip/hip_runtime.h>
#include <stdint.h>
#include <stddef.h>

#define B_ 16
#define T_ 1024
#define F_ 80
#define D_ 512
#define M_ 16384   // T*B rows, row index = t*16 + b
#define VO 29      // V+1
#define SENT 0x7FC07FC0u
#define GPH 5      // gx-ring phases (sentinel-based, reset 1 ahead)

typedef float f32x4 __attribute__((ext_vector_type(4)));
typedef short s16x8 __attribute__((ext_vector_type(8)));
typedef unsigned short u16x8 __attribute__((ext_vector_type(8)));

static __device__ __forceinline__ unsigned short f2bf(float f) {
    union { float f; unsigned u; } v; v.f = f;
    unsigned r = v.u + 0x7FFFu + ((v.u >> 16) & 1u);
    return (unsigned short)(r >> 16);
}
static __device__ __forceinline__ float bf2f(unsigned short h) {
    union { unsigned u; float f; } v; v.u = ((unsigned)h) << 16; return v.f;
}
static __device__ __forceinline__ void split2(float v, unsigned short& hi, unsigned short& lo) {
    hi = f2bf(v);
    lo = f2bf(v - bf2f(hi));
}
static __device__ __forceinline__ float sigm(float x) {
    return 1.0f / (1.0f + __expf(-x));
}
static __device__ __forceinline__ float fast_tanh(float x) {
    return 1.0f - 2.0f / (__expf(2.0f * x) + 1.0f);
}
static __device__ __forceinline__ float wred(float v) {
    #pragma unroll
    for (int off = 1; off < 64; off <<= 1) v += __shfl_xor(v, off, 64);
    return v;
}
static __device__ __forceinline__ void stf_agent(float* p, float v) {
    union { float f; unsigned u; } c; c.f = v;
    __hip_atomic_store((unsigned*)p, c.u, __ATOMIC_RELAXED, __HIP_MEMORY_SCOPE_AGENT);
}
// async global->LDS, 16B per lane
static __device__ __forceinline__ void gload16(const void* g, void* lds) {
    __builtin_amdgcn_global_load_lds(
        (const __attribute__((address_space(1))) void*)g,
        (__attribute__((address_space(3))) void*)lds, 16, 0, 0);
}

// ---------------- weight conversion (fp32 -> bf16 hi/lo split) ----------------
__global__ __launch_bounds__(256) void conv_w0(const float* __restrict__ W,
        unsigned short* __restrict__ Bh, unsigned short* __restrict__ Bl) {
    int gid = blockIdx.x * 256 + threadIdx.x;     // 2048*96
    int n = gid / 96, k = gid - n * 96;
    float v = (k < 80) ? W[(size_t)k * 2048 + n] : 0.0f;
    unsigned short h, l; split2(v, h, l);
    Bh[gid] = h; Bl[gid] = l;
}
__global__ __launch_bounds__(256) void conv_sruw1(const float* __restrict__ W,
        unsigned short* __restrict__ Bh, unsigned short* __restrict__ Bl) {
    int gid = blockIdx.x * 256 + threadIdx.x;     // 1536*512
    int n = gid >> 9, k = gid & 511;
    float v = W[(size_t)k * 1536 + n];
    unsigned short h, lo; split2(v, h, lo);
    Bh[gid] = h; Bl[gid] = lo;
}
__global__ __launch_bounds__(256) void conv_split(const float* __restrict__ W,
        unsigned short* __restrict__ Oh, unsigned short* __restrict__ Ol, int n) {
    int gid = blockIdx.x * 256 + threadIdx.x;
    if (gid < n) {
        unsigned short h, l; split2(W[gid], h, l);
        Oh[gid] = h; Ol[gid] = l;
    }
}
__global__ __launch_bounds__(256) void sent_fill(unsigned int* __restrict__ buf, int n) {
    int gid = blockIdx.x * 256 + threadIdx.x;
    if (gid < n)
        __hip_atomic_store(&buf[gid], SENT, __ATOMIC_RELAXED, __HIP_MEMORY_SCOPE_AGENT);
}
__global__ void zero_ctl(unsigned int* c) {
    if (threadIdx.x < 160)
        __hip_atomic_store(&c[threadIdx.x], 0u, __ATOMIC_RELAXED, __HIP_MEMORY_SCOPE_AGENT);
}

// ---------------- LayerNorm kernels ----------------
__global__ __launch_bounds__(256) void ln80_kernel(const float* __restrict__ x,
        const float* __restrict__ g, const float* __restrict__ bta,
        unsigned short* __restrict__ xh, unsigned short* __restrict__ xl) {
    int w = threadIdx.x >> 6, lane = threadIdx.x & 63;
    int row = blockIdx.x * 4 + w;          // row = t*16 + b
    int b = row & 15, t = row >> 4;
    const float* xr = x + ((size_t)b * T_ + t) * F_;
    float v0 = xr[lane];
    float v1 = (lane < 16) ? xr[64 + lane] : 0.0f;
    float mean = wred(v0 + v1) * (1.0f / 80.0f);
    float d0 = v0 - mean;
    float d1 = (lane < 16) ? (v1 - mean) : 0.0f;
    float var = wred(d0 * d0 + d1 * d1) * (1.0f / 80.0f);
    float rstd = rsqrtf(var + 1e-5f);
    float o0 = d0 * rstd * g[lane] + bta[lane];
    unsigned short h, l; split2(o0, h, l);
    xh[(size_t)row * 96 + lane] = h;
    xl[(size_t)row * 96 + lane] = l;
    if (lane < 32) {
        unsigned short hv = 0, lv = 0;
        if (lane < 16) {
            float o1 = d1 * rstd * g[64 + lane] + bta[64 + lane];
            split2(o1, hv, lv);
        }
        xh[(size_t)row * 96 + 64 + lane] = hv;
        xl[(size_t)row * 96 + 64 + lane] = lv;
    }
}

__global__ __launch_bounds__(256) void ln512_bf16(const float* __restrict__ hsrc,
        const float* __restrict__ g, const float* __restrict__ bta,
        unsigned short* __restrict__ oh, unsigned short* __restrict__ ol) {
    int w = threadIdx.x >> 6, lane = threadIdx.x & 63;
    size_t row = (size_t)blockIdx.x * 4 + w;
    const float* hr = hsrc + row * D_;
    float4 p0 = *(const float4*)(hr + lane * 8);
    float4 p1 = *(const float4*)(hr + lane * 8 + 4);
    float s = p0.x + p0.y + p0.z + p0.w + p1.x + p1.y + p1.z + p1.w;
    float mean = wred(s) * (1.0f / 512.0f);
    float d[8] = {p0.x - mean, p0.y - mean, p0.z - mean, p0.w - mean,
                  p1.x - mean, p1.y - mean, p1.z - mean, p1.w - mean};
    float q = 0.f;
    #pragma unroll
    for (int i = 0; i < 8; ++i) q += d[i] * d[i];
    float rstd = rsqrtf(wred(q) * (1.0f / 512.0f) + 1e-5f);
    const float* gp = g + lane * 8;
    const float* bp = bta + lane * 8;
    u16x8 vh, vl;
    #pragma unroll
    for (int i = 0; i < 8; ++i) {
        float o = d[i] * rstd * gp[i] + bp[i];
        unsigned short hh, ll; split2(o, hh, ll);
        vh[i] = hh; vl[i] = ll;
    }
    *(u16x8*)(oh + row * D_ + lane * 8) = vh;
    *(u16x8*)(ol + row * D_ + lane * 8) = vl;
}

__global__ __launch_bounds__(256) void ln512_f32(const float* __restrict__ hsrc,
        const float* __restrict__ g, const float* __restrict__ bta,
        float* __restrict__ o) {
    int w = threadIdx.x >> 6, lane = threadIdx.x & 63;
    size_t row = (size_t)blockIdx.x * 4 + w;
    const float* hr = hsrc + row * D_;
    float4 p0 = *(const float4*)(hr + lane * 8);
    float4 p1 = *(const float4*)(hr + lane * 8 + 4);
    float s = p0.x + p0.y + p0.z + p0.w + p1.x + p1.y + p1.z + p1.w;
    float mean = wred(s) * (1.0f / 512.0f);
    float d[8] = {p0.x - mean, p0.y - mean, p0.z - mean, p0.w - mean,
                  p1.x - mean, p1.y - mean, p1.z - mean, p1.w - mean};
    float q = 0.f;
    #pragma unroll
    for (int i = 0; i < 8; ++i) q += d[i] * d[i];
    float rstd = rsqrtf(wred(q) * (1.0f / 512.0f) + 1e-5f);
    const float* gp = g + lane * 8;
    const float* bp = bta + lane * 8;
    float* op = o + row * D_ + lane * 8;
    #pragma unroll
    for (int i = 0; i < 8; ++i) op[i] = d[i] * rstd * gp[i] + bp[i];
}

// ------- split bf16 MFMA GEMM, 128x128 tile, global_load_lds + XOR swizzle -------
__global__ __launch_bounds__(256) void gemm_split(
        const unsigned short* __restrict__ Ah, const unsigned short* __restrict__ Al,
        const unsigned short* __restrict__ Bh, const unsigned short* __restrict__ Bl,
        float* __restrict__ C, int N, int Kp,
        const float* __restrict__ bias0, const float* __restrict__ bias1) {
    __shared__ __align__(16) unsigned short sAh[4096];
    __shared__ __align__(16) unsigned short sAl[4096];
    __shared__ __align__(16) unsigned short sBh[4096];
    __shared__ __align__(16) unsigned short sBl[4096];
    const int tid = threadIdx.x;
    const int wv = tid >> 6, lane = tid & 63;
    const int c_ = lane & 15, r_ = lane >> 4;
    const int wr = wv >> 1, wc = wv & 1;
    const int mBase = blockIdx.y * 128, nBase = blockIdx.x * 128;

    const int row0 = tid >> 2, row1 = 64 + row0;
    const int sp = tid & 3;
    const int x0 = (row0 & 3) ^ ((row0 >> 2) & 3);
    const int x1 = (row1 & 3) ^ ((row1 >> 2) & 3);
    const size_t gA0 = (size_t)(mBase + row0) * Kp + (size_t)((sp ^ x0) * 8);
    const size_t gA1 = (size_t)(mBase + row1) * Kp + (size_t)((sp ^ x1) * 8);
    const size_t gB0 = (size_t)(nBase + row0) * Kp + (size_t)((sp ^ x0) * 8);
    const size_t gB1 = (size_t)(nBase + row1) * Kp + (size_t)((sp ^ x1) * 8);
    const int ldsW = wv * 1024;

    int offA[4], offB[4];
    #pragma unroll
    for (int f = 0; f < 4; ++f) {
        int ra = wr * 64 + f * 16 + c_;
        int xa = (ra & 3) ^ ((ra >> 2) & 3);
        offA[f] = ra * 32 + ((r_ ^ xa) * 8);
        int rb = wc * 64 + f * 16 + c_;
        int xb = (rb & 3) ^ ((rb >> 2) & 3);
        offB[f] = rb * 32 + ((r_ ^ xb) * 8);
    }

    f32x4 acc[4][4] = {};
    for (int kt = 0; kt < Kp; kt += 32) {
        gload16(Ah + gA0 + kt, (char*)sAh + ldsW);
        gload16(Ah + gA1 + kt, (char*)sAh + 4096 + ldsW);
        gload16(Al + gA0 + kt, (char*)sAl + ldsW);
        gload16(Al + gA1 + kt, (char*)sAl + 4096 + ldsW);
        gload16(Bh + gB0 + kt, (char*)sBh + ldsW);
        gload16(Bh + gB1 + kt, (char*)sBh + 4096 + ldsW);
        gload16(Bl + gB0 + kt, (char*)sBl + ldsW);
        gload16(Bl + gB1 + kt, (char*)sBl + 4096 + ldsW);
        __syncthreads();
        s16x8 ah[4], al[4], bh[4], bl[4];
        #pragma unroll
        for (int f = 0; f < 4; ++f) {
            ah[f] = *(const s16x8*)&sAh[offA[f]];
            al[f] = *(const s16x8*)&sAl[offA[f]];
            bh[f] = *(const s16x8*)&sBh[offB[f]];
            bl[f] = *(const s16x8*)&sBl[offB[f]];
        }
        #pragma unroll
        for (int mf = 0; mf < 4; ++mf) {
            #pragma unroll
            for (int nf = 0; nf < 4; ++nf) {
                acc[mf][nf] = __builtin_amdgcn_mfma_f32_16x16x32_bf16(ah[mf], bh[nf], acc[mf][nf], 0, 0, 0);
                acc[mf][nf] = __builtin_amdgcn_mfma_f32_16x16x32_bf16(al[mf], bh[nf], acc[mf][nf], 0, 0, 0);
                acc[mf][nf] = __builtin_amdgcn_mfma_f32_16x16x32_bf16(ah[mf], bl[nf], acc[mf][nf], 0, 0, 0);
            }
        }
        __syncthreads();
    }
    #pragma unroll
    for (int mf = 0; mf < 4; ++mf) {
        #pragma unroll
        for (int r = 0; r < 4; ++r) {
            int m = mBase + wr * 64 + mf * 16 + r_ * 4 + r;
            float* crow = C + (size_t)m * N + nBase + wc * 64;
            #pragma unroll
            for (int nf = 0; nf < 4; ++nf) {
                int n = nBase + wc * 64 + nf * 16 + c_;
                float v = acc[mf][nf][r];
                if (bias0) v += bias0[n];
                if (bias1) v += bias1[n];
                crow[nf * 16 + c_] = v;
            }
        }
    }
}

// ---------------- SRU recurrence ----------------
__global__ __launch_bounds__(64) void sru_rec(const float* __restrict__ U, int NU,
        const float* __restrict__ xprev, const float* __restrict__ wc,
        const float* __restrict__ bias, float* __restrict__ hout) {
    int gid = blockIdx.x * 64 + threadIdx.x;
    int d = gid & (D_ - 1), b = gid >> 9;
    float vf = wc[d], vr = wc[D_ + d];
    float bf = bias[d], br = bias[D_ + d];
    const float* u0 = U + d;
    const float* u1 = U + D_ + d;
    const float* u2 = U + 2 * D_ + d;
    const float* xr;  size_t xstride;
    if (xprev) { xr = xprev + d; xstride = D_; }
    else       { xr = U + 3 * (size_t)D_ + d; xstride = (size_t)NU; }
    float* ho = hout + d;
    float c = 0.f;
    #pragma unroll 4
    for (int t = 0; t < T_; ++t) {
        size_t row = (size_t)(t * 16 + b);
        float a0 = u0[row * NU];
        float a1 = u1[row * NU];
        float a2 = u2[row * NU];
        float xv = xr[row * xstride];
        float f = sigm(a1 + vf * c + bf);
        float r = sigm(a2 + vr * c + br);
        c = f * c + (1.f - f) * a0;
        float h = r * c + (1.f - r) * xv;
        ho[row * D_] = h;
    }
}

// =================== 3-layer pipelined LSTM (persistent, 112 WGs) ===================
// Roles: [0,16) LSTM L0 | [16,32) L1 | [32,48) L2 | [48,80) crew1 | [80,112) crew2.
// h-rings: 3-phase sentinel rings, HI-PLANE ONLY (r14): the h_lo x W_hi term
// contributes ~6e-4 to gate pre-activations (contracting recurrence) -> dropped.
// Halves publish/poll traffic, removes 2 of 6 MFMAs. W_lo (h_hi x W_lo) kept.
// gx-rings: 5-slot NaN-sentinel (r13 proven).

template <int MODE>
static __device__ void lstm_role(int wg, const float* gxsrc,
        const unsigned short* Wh, const unsigned short* Wl,
        unsigned* ring, unsigned* myLprog,
        const unsigned* consCprog, float* hout) {
    __shared__ __align__(16) unsigned short hH[16][520];
    __shared__ float G[16][132];
    const int tid = threadIdx.x;
    const int w = tid >> 6, lane = tid & 63;
    const int c_ = lane & 15, r_ = lane >> 4;

    s16x8 bh0[16], bh1[16], bl0[16], bl1[16];
    {
        size_t R0 = (size_t)(w * 512 + wg * 32 + c_) * 512;
        size_t R1 = R0 + 16 * 512;
        #pragma unroll
        for (int ks = 0; ks < 16; ++ks) {
            bh0[ks] = *(const s16x8*)(Wh + R0 + ks * 32 + r_ * 8);
            bh1[ks] = *(const s16x8*)(Wh + R1 + ks * 32 + r_ * 8);
            bl0[ks] = *(const s16x8*)(Wl + R0 + ks * 32 + r_ * 8);
            bl1[ks] = *(const s16x8*)(Wl + R1 + ks * 32 + r_ * 8);
        }
    }
    for (int i = tid; i < 16 * 520; i += 256)
        ((unsigned short*)hH)[i] = 0;
    const int eb = tid >> 4;
    const int ed = (tid * 2) & 31;
    float cc0 = 0.f, cc1 = 0.f;
    const int col0 = w * 512 + wg * 32 + c_;
    const int hidx = (eb * 512 + wg * 32 + ed) >> 1;

    float gxv0[4], gxv1[4];
    if (MODE == 0) {
        #pragma unroll
        for (int r = 0; r < 4; ++r) {
            int bt = r_ * 4 + r;
            gxv0[r] = gxsrc[(size_t)bt * 2048 + col0];
            gxv1[r] = gxsrc[(size_t)bt * 2048 + col0 + 16];
        }
    } else {
        // initial fetch of gx_0: sentinel poll of slot 0
        const float* gs = gxsrc;
        unsigned gv[8];
        unsigned gb = 0xFFu;
        while (true) {
            #pragma unroll
            for (int r = 0; r < 4; ++r) {
                int bt = r_ * 4 + r;
                if (gb & (1u << r))
                    gv[r] = __hip_atomic_load((const unsigned*)(gs + (size_t)bt * 2048 + col0),
                                              __ATOMIC_RELAXED, __HIP_MEMORY_SCOPE_AGENT);
                if (gb & (1u << (4 + r)))
                    gv[4 + r] = __hip_atomic_load((const unsigned*)(gs + (size_t)bt * 2048 + col0 + 16),
                                                  __ATOMIC_RELAXED, __HIP_MEMORY_SCOPE_AGENT);
            }
            unsigned nb = 0u;
            #pragma unroll
            for (int r = 0; r < 8; ++r)
                if ((gv[r] >> 16) == 0x7FC0u) nb |= 1u << r;
            gb = nb;
            if (!__any(gb != 0u)) break;
            __builtin_amdgcn_s_sleep(1);
        }
        #pragma unroll
        for (int r = 0; r < 4; ++r) {
            union { unsigned u; float f; } c0, c1;
            c0.u = gv[r]; c1.u = gv[4 + r];
            gxv0[r] = c0.f; gxv1[r] = c1.f;
        }
    }
    int pcur = 0, pnxt = 4096, pthr = 8192;   // hi-only: 4096 dwords/phase
    __syncthreads();

    for (int t = 0; t < T_; ++t) {
        if (MODE == 1 && tid == 0)
            __hip_atomic_store(&myLprog[wg], (unsigned)t, __ATOMIC_RELAXED, __HIP_MEMORY_SCOPE_AGENT);
        // crew-ack gate: crew must have consumed h_{t-2} before we reset its slot
        if (consCprog) {
            int lim = t - 1;
            while (true) {
                int p = (int)__hip_atomic_load(&consCprog[lane & 31],
                                               __ATOMIC_RELAXED, __HIP_MEMORY_SCOPE_AGENT);
                if (__all(p >= lim)) break;
                __builtin_amdgcn_s_sleep(2);
            }
        }
        __hip_atomic_store(&ring[pnxt + hidx], SENT, __ATOMIC_RELAXED, __HIP_MEMORY_SCOPE_AGENT);
        f32x4 acc0 = {0.f, 0.f, 0.f, 0.f};
        f32x4 acc1 = {0.f, 0.f, 0.f, 0.f};
        #pragma unroll
        for (int ks = 0; ks < 16; ++ks) {
            s16x8 ah = *(const s16x8*)&hH[c_][ks * 32 + r_ * 8];
            acc0 = __builtin_amdgcn_mfma_f32_16x16x32_bf16(ah, bh0[ks], acc0, 0, 0, 0);
            acc1 = __builtin_amdgcn_mfma_f32_16x16x32_bf16(ah, bh1[ks], acc1, 0, 0, 0);
            acc0 = __builtin_amdgcn_mfma_f32_16x16x32_bf16(ah, bl0[ks], acc0, 0, 0, 0);
            acc1 = __builtin_amdgcn_mfma_f32_16x16x32_bf16(ah, bl1[ks], acc1, 0, 0, 0);
        }
        #pragma unroll
        for (int r = 0; r < 4; ++r) {
            int bt = r_ * 4 + r;
            G[bt][w * 32 + c_]      = acc0[r] + gxv0[r];
            G[bt][w * 32 + 16 + c_] = acc1[r] + gxv1[r];
        }
        __syncthreads();
        float iv0 = G[eb][ed],     fv0 = G[eb][32 + ed], gv0 = G[eb][64 + ed], ov0 = G[eb][96 + ed];
        float iv1 = G[eb][ed + 1], fv1 = G[eb][33 + ed], gv1 = G[eb][65 + ed], ov1 = G[eb][97 + ed];
        cc0 = sigm(fv0) * cc0 + sigm(iv0) * fast_tanh(gv0);
        cc1 = sigm(fv1) * cc1 + sigm(iv1) * fast_tanh(gv1);
        float h0 = sigm(ov0) * fast_tanh(cc0);
        float h1 = sigm(ov1) * fast_tanh(cc1);
        asm volatile("s_waitcnt vmcnt(0)" ::: "memory");
        unsigned packH = (unsigned)f2bf(h0) | ((unsigned)f2bf(h1) << 16);
        __hip_atomic_store(&ring[pcur + hidx], packH, __ATOMIC_RELAXED, __HIP_MEMORY_SCOPE_AGENT);
        if (hout) {
            size_t orow = (size_t)(t * 16 + eb) * D_ + wg * 32 + ed;
            hout[orow] = h0; hout[orow + 1] = h1;
        }
        if (t == T_ - 1) break;
        // prefetch gx_{t+1} (cached for MODE 0; sentinel-poll of gx-ring for MODE 1)
        if (MODE == 0) {
            const float* gxr = gxsrc + (size_t)((t + 1) * 16) * 2048;
            #pragma unroll
            for (int r = 0; r < 4; ++r) {
                int bt = r_ * 4 + r;
                gxv0[r] = gxr[(size_t)bt * 2048 + col0];
                gxv1[r] = gxr[(size_t)bt * 2048 + col0 + 16];
            }
        } else {
            const float* gs = gxsrc + (size_t)((t + 1) % GPH) * 32768;
            unsigned gv[8];
            unsigned gb = 0xFFu;
            while (true) {
                #pragma unroll
                for (int r = 0; r < 4; ++r) {
                    int bt = r_ * 4 + r;
                    if (gb & (1u << r))
                        gv[r] = __hip_atomic_load((const unsigned*)(gs + (size_t)bt * 2048 + col0),
                                                  __ATOMIC_RELAXED, __HIP_MEMORY_SCOPE_AGENT);
                    if (gb & (1u << (4 + r)))
                        gv[4 + r] = __hip_atomic_load((const unsigned*)(gs + (size_t)bt * 2048 + col0 + 16),
                                                      __ATOMIC_RELAXED, __HIP_MEMORY_SCOPE_AGENT);
                }
                unsigned nb = 0u;
                #pragma unroll
                for (int r = 0; r < 8; ++r)
                    if ((gv[r] >> 16) == 0x7FC0u) nb |= 1u << r;
                gb = nb;
                if (!__any(gb != 0u)) break;
                __builtin_amdgcn_s_sleep(1);
            }
            #pragma unroll
            for (int r = 0; r < 4; ++r) {
                union { unsigned u; float f; } c0, c1;
                c0.u = gv[r]; c1.u = gv[4 + r];
                gxv0[r] = c0.f; gxv1[r] = c1.f;
            }
        }
        // ---- h-ring sentinel poll (hi plane only) with repair re-reads ----
        unsigned long long vh[8];
        unsigned badm = 0xFFu;
        while (true) {
            #pragma unroll
            for (int j = 0; j < 8; ++j) {
                int q = pcur + j * 512 + tid * 2;
                if (badm & (1u << j))
                    vh[j] = __hip_atomic_load((const unsigned long long*)&ring[q],
                                              __ATOMIC_RELAXED, __HIP_MEMORY_SCOPE_AGENT);
            }
            unsigned nb = 0u;
            #pragma unroll
            for (int j = 0; j < 8; ++j) {
                unsigned a0 = (unsigned)vh[j], a1 = (unsigned)(vh[j] >> 32);
                if (((a0 >> 16) == 0x7FC0u) || ((a1 >> 16) == 0x7FC0u)) nb |= 1u << j;
            }
            badm = nb;
            if (!__any(badm != 0u)) break;
            __builtin_amdgcn_s_sleep(1);
        }
        #pragma unroll
        for (int j = 0; j < 8; ++j) {
            int q = j * 512 + tid * 2;
            int bb = q >> 8, dd = (q & 255) * 2;
            *(unsigned long long*)&hH[bb][dd] = vh[j];
        }
        __syncthreads();
        int tmp = pcur; pcur = pnxt; pnxt = pthr; pthr = tmp;
    }
}

// crew: per step, LN(h^l_t) then gx^{l+1}_t tile (64 cols) via 3-term MFMA.
// h read hi-only from ring; gx published via sentinel ring (no flag, no post-drain).
static __device__ void crew_role(int cid, const unsigned* srcring, float* gxr,
        unsigned* cprog, const unsigned* lprog,
        const unsigned short* WihHp, const unsigned short* WihLp,
        const float* g, const float* bta,
        const float* bihp, const float* bhhp) {
    __shared__ __align__(16) unsigned short xnH[16][520];
    __shared__ __align__(16) unsigned short xnL[16][520];
    const int tid = threadIdx.x;
    const int w = tid >> 6, lane = tid & 63;
    const int c_ = lane & 15, r_ = lane >> 4;
    const int col = cid * 64 + w * 16 + c_;
    const int rr = w * 4 + r_;          // LN row owned by this lane

    s16x8 bfh[16], bfl[16];
    {
        const unsigned short* wrH = WihHp + (size_t)col * 512;
        const unsigned short* wrL = WihLp + (size_t)col * 512;
        #pragma unroll
        for (int ks = 0; ks < 16; ++ks) {
            bfh[ks] = *(const s16x8*)(wrH + ks * 32 + r_ * 8);
            bfl[ks] = *(const s16x8*)(wrL + ks * 32 + r_ * 8);
        }
    }
    const float bias = bihp[col] + bhhp[col];
    float lg[32], lb[32];
    #pragma unroll
    for (int j = 0; j < 32; ++j) { lg[j] = g[c_ * 32 + j]; lb[j] = bta[c_ * 32 + j]; }

    for (int t = 0; t < T_; ++t) {
        // gx-ring gate: guards the reset of slot (t+1)%GPH and stores to slot t%GPH
        {
            int lim = t - 3;
            while (true) {
                int p = (int)__hip_atomic_load(&lprog[lane & 15],
                                               __ATOMIC_RELAXED, __HIP_MEMORY_SCOPE_AGENT);
                if (__all(p >= lim)) break;
                __builtin_amdgcn_s_sleep(2);
            }
        }
        // reset own words of slot (t+1)%GPH (drained before this step's data stores)
        {
            unsigned* rs = (unsigned*)(gxr + (size_t)((t + 1) % GPH) * 32768);
            #pragma unroll
            for (int r = 0; r < 4; ++r)
                __hip_atomic_store(&rs[(size_t)(r_ * 4 + r) * 2048 + col], SENT,
                                   __ATOMIC_RELAXED, __HIP_MEMORY_SCOPE_AGENT);
        }
        // sentinel-poll h^l_t (hi plane, own LN window) with repair re-reads
        const unsigned* sb = srcring + (t % 3) * 4096;
        const int qi = rr * 256 + c_ * 16;
        unsigned long long vh[8];
        unsigned badm = 0xFFu;
        while (true) {
            #pragma unroll
            for (int j = 0; j < 8; ++j) {
                if (badm & (1u << j))
                    vh[j] = __hip_atomic_load((const unsigned long long*)&sb[qi + j * 2],
                                              __ATOMIC_RELAXED, __HIP_MEMORY_SCOPE_AGENT);
            }
            unsigned nb = 0u;
            #pragma unroll
            for (int j = 0; j < 8; ++j) {
                unsigned a0 = (unsigned)vh[j], a1 = (unsigned)(vh[j] >> 32);
                if (((a0 >> 16) == 0x7FC0u) || ((a1 >> 16) == 0x7FC0u)) nb |= 1u << j;
            }
            badm = nb;
            if (!__any(badm != 0u)) break;
            __builtin_amdgcn_s_sleep(1);
        }
        // reconstruct 32 fp32 values (hi-only)
        float x[32];
        #pragma unroll
        for (int k = 0; k < 8; ++k) {
            unsigned ah = (unsigned)vh[k], bh = (unsigned)(vh[k] >> 32);
            x[4 * k + 0] = bf2f((unsigned short)ah);
            x[4 * k + 1] = bf2f((unsigned short)(ah >> 16));
            x[4 * k + 2] = bf2f((unsigned short)bh);
            x[4 * k + 3] = bf2f((unsigned short)(bh >> 16));
        }
        // LN across the 16-lane row group
        float s = 0.f;
        #pragma unroll
        for (int j = 0; j < 32; ++j) s += x[j];
        #pragma unroll
        for (int m = 1; m < 16; m <<= 1) s += __shfl_xor(s, m, 64);
        float mean = s * (1.0f / 512.0f);
        float q = 0.f;
        #pragma unroll
        for (int j = 0; j < 32; ++j) { float d = x[j] - mean; q += d * d; }
        #pragma unroll
        for (int m = 1; m < 16; m <<= 1) q += __shfl_xor(q, m, 64);
        float rstd = rsqrtf(q * (1.0f / 512.0f) + 1e-5f);
        u16x8 ph[4], pl[4];
        #pragma unroll
        for (int j = 0; j < 32; ++j) {
            float o = (x[j] - mean) * rstd * lg[j] + lb[j];
            unsigned short hh, ll; split2(o, hh, ll);
            ph[j >> 3][j & 7] = (unsigned short)hh;
            pl[j >> 3][j & 7] = (unsigned short)ll;
        }
        #pragma unroll
        for (int jj = 0; jj < 4; ++jj) {
            *(u16x8*)&xnH[rr][c_ * 32 + jj * 8] = ph[jj];
            *(u16x8*)&xnL[rr][c_ * 32 + jj * 8] = pl[jj];
        }
        __syncthreads();
        if (tid == 0)
            __hip_atomic_store(&cprog[cid], (unsigned)(t + 1), __ATOMIC_RELAXED, __HIP_MEMORY_SCOPE_AGENT);
        // MFMA: gx tile = xn @ wih_slice^T (+biases), 3-term split
        f32x4 acc = {bias, bias, bias, bias};
        #pragma unroll
        for (int ks = 0; ks < 16; ++ks) {
            s16x8 axh = *(const s16x8*)&xnH[c_][ks * 32 + r_ * 8];
            s16x8 axl = *(const s16x8*)&xnL[c_][ks * 32 + r_ * 8];
            acc = __builtin_amdgcn_mfma_f32_16x16x32_bf16(axh, bfh[ks], acc, 0, 0, 0);
            acc = __builtin_amdgcn_mfma_f32_16x16x32_bf16(axl, bfh[ks], acc, 0, 0, 0);
            acc = __builtin_amdgcn_mfma_f32_16x16x32_bf16(axh, bfl[ks], acc, 0, 0, 0);
        }
        // drain BEFORE data stores: resets visible first; consumers detect via data
        asm volatile("s_waitcnt vmcnt(0)" ::: "memory");
        float* gs = gxr + (size_t)(t % GPH) * 32768;
        #pragma unroll
        for (int r = 0; r < 4; ++r)
            stf_agent(gs + (size_t)(r_ * 4 + r) * 2048 + col, acc[r]);
        __syncthreads();   // xn reads done before next step's writes
    }
}

__global__ __launch_bounds__(256, 1) void lstm_pipe(
        const float* __restrict__ gx0,
        const unsigned short* __restrict__ WhhH, const unsigned short* __restrict__ WhhL,
        const unsigned short* __restrict__ WihH, const unsigned short* __restrict__ WihL,
        const float* __restrict__ lng, const float* __restrict__ lnb,
        const float* __restrict__ bih, const float* __restrict__ bhh,
        float* __restrict__ hout,
        unsigned* __restrict__ rings,   // [3][3*4096]  (hi-only)
        float* __restrict__ gxr,        // [2][GPH*32768]
        unsigned* __restrict__ ctl) {   // Lp1[16]@64, Lp2[16]@80, Cp1[32]@96, Cp2[32]@128
    const int bid = blockIdx.x;
    const size_t WSL = (size_t)2048 * 512;
    const int RNG = 3 * 4096;
    if (bid < 16) {
        lstm_role<0>(bid, gx0, WhhH, WhhL, rings,
                     nullptr, ctl + 96, nullptr);
    } else if (bid < 32) {
        lstm_role<1>(bid - 16, gxr, WhhH + WSL, WhhL + WSL, rings + RNG,
                     ctl + 64, ctl + 128, nullptr);
    } else if (bid < 48) {
        lstm_role<1>(bid - 32, gxr + (size_t)GPH * 32768, WhhH + 2 * WSL, WhhL + 2 * WSL,
                     rings + 2 * RNG, ctl + 80, nullptr, hout);
    } else if (bid < 80) {
        crew_role(bid - 48, rings, gxr, ctl + 96, ctl + 64,
                  WihH, WihL, lng + 512, lnb + 512, bih + 2048, bhh + 2048);
    } else {
        crew_role(bid - 80, rings + RNG, gxr + (size_t)GPH * 32768, ctl + 128, ctl + 80,
                  WihH + WSL, WihL + WSL, lng + 1024, lnb + 1024, bih + 4096, bhh + 4096);
    }
}

// ---------------- classifier ----------------
__global__ __launch_bounds__(256) void cls_gemm(const float* __restrict__ xn,
        const float* __restrict__ wcls, float* __restrict__ out) {
    __shared__ float wl[512][32];
    int tid = threadIdx.x;
    for (int idx = tid; idx < 512 * VO; idx += 256) {
        int k = idx / VO, v = idx - k * VO;
        wl[k][v] = wcls[idx];
    }
    __syncthreads();
    int r8 = tid >> 5, v = tid & 31;
    int row = blockIdx.x * 8 + r8;
    if (v >= VO) return;
    const float* xr = xn + (size_t)row * D_;
    float acc = 0.f;
    #pragma unroll 8
    for (int k = 0; k < 512; ++k) acc += xr[k] * wl[k][v];
    int b = row & 15, t = row >> 4;
    out[((size_t)b * T_ + t) * VO + v] = acc;
}

// ------------------------------- launch ------------------------------------------
extern "C" void kernel_launch(void* const* d_in, const int* in_sizes, int n_in,
                              void* d_out, int out_size, void* d_ws, size_t ws_size,
                              hipStream_t stream) {
    const float* x        = (const float*)d_in[0];
    const float* sru_w0   = (const float*)d_in[1];
    const float* sru_wc0  = (const float*)d_in[2];
    const float* sru_b0   = (const float*)d_in[3];
    const float* sru_ln0g = (const float*)d_in[4];
    const float* sru_ln0b = (const float*)d_in[5];
    const float* sru_w    = (const float*)d_in[6];
    const float* sru_wc   = (const float*)d_in[7];
    const float* sru_b    = (const float*)d_in[8];
    const float* sru_lng  = (const float*)d_in[9];
    const float* sru_lnb  = (const float*)d_in[10];
    const float* lstm_lng = (const float*)d_in[11];
    const float* lstm_lnb = (const float*)d_in[12];
    const float* lstm_wih = (const float*)d_in[13];
    const float* lstm_whh = (const float*)d_in[14];
    const float* lstm_bih = (const float*)d_in[15];
    const float* lstm_bhh = (const float*)d_in[16];
    const float* cls_lng  = (const float*)d_in[17];
    const float* cls_lnb  = (const float*)d_in[18];
    const float* cls_w    = (const float*)d_in[19];
    float* out = (float*)d_out;

    char* ws = (char*)d_ws;
    size_t off = 0;
    auto alloc = [&](size_t bytes) -> void* {
        off = (off + 255) & ~(size_t)255;
        void* p = ws + off;
        off += bytes;
        return p;
    };
    float* U             = (float*)alloc((size_t)M_ * 1536 * 4);
    float* hP            = (float*)alloc((size_t)M_ * D_ * 4);     // contiguous after U
    float* hQ            = (float*)alloc((size_t)M_ * D_ * 4);
    unsigned short* xnh  = (unsigned short*)alloc((size_t)M_ * D_ * 2);
    unsigned short* xnl  = (unsigned short*)alloc((size_t)M_ * D_ * 2);
    unsigned short* w0h  = (unsigned short*)alloc((size_t)2048 * 96 * 2);
    unsigned short* w0l  = (unsigned short*)alloc((size_t)2048 * 96 * 2);
    unsigned short* swh  = (unsigned short*)alloc((size_t)1536 * 512 * 2);  // SRU per-layer reuse
    unsigned short* swl  = (unsigned short*)alloc((size_t)1536 * 512 * 2);
    unsigned short* wihh = (unsigned short*)alloc((size_t)2048 * 512 * 2);  // LSTM layer-0 wih
    unsigned short* wihl = (unsigned short*)alloc((size_t)2048 * 512 * 2);
    unsigned short* whh3h = (unsigned short*)alloc((size_t)3 * 2048 * 512 * 2);
    unsigned short* whh3l = (unsigned short*)alloc((size_t)3 * 2048 * 512 * 2);
    unsigned short* wih2h = (unsigned short*)alloc((size_t)2 * 2048 * 512 * 2);
    unsigned short* wih2l = (unsigned short*)alloc((size_t)2 * 2048 * 512 * 2);
    // rings/gxr/ctl alias the SRU weight buffers (dead after SRU layers)
    unsigned* rings = (unsigned*)swh;                              // 3*3*4096*4 = 144 KB < 1.5 MB
    float*    gxr   = (float*)swl;                                 // 2*GPH*32768*4 = 1.25 MB < 1.5 MB
    unsigned* ctl   = (unsigned*)(((char*)swh) + 3 * 3 * 4096 * 4);
    float* gx = U;   // 2048-wide gx0 spans [U | hP] contiguously

    hipLaunchKernelGGL(conv_w0, dim3(768), dim3(256), 0, stream, sru_w0, w0h, w0l);

    // ---- SRU layer 0 (gx = [U|hP], output -> hQ) ----
    hipLaunchKernelGGL(ln80_kernel, dim3(4096), dim3(256), 0, stream, x, sru_ln0g, sru_ln0b, xnh, xnl);
    hipLaunchKernelGGL(gemm_split, dim3(2048 / 128, M_ / 128), dim3(256), 0, stream,
                       xnh, xnl, w0h, w0l, gx, 2048, 96, (const float*)nullptr, (const float*)nullptr);
    hipLaunchKernelGGL(sru_rec, dim3(128), dim3(64), 0, stream,
                       gx, 2048, (const float*)nullptr, sru_wc0, sru_b0, hQ);

    float* hcur = hQ; float* hnxt = hP;
    // ---- SRU layers 1..7 ----
    for (int l = 0; l < 7; ++l) {
        hipLaunchKernelGGL(conv_sruw1, dim3(3072), dim3(256), 0, stream,
                           sru_w + (size_t)l * 512 * 1536, swh, swl);
        hipLaunchKernelGGL(ln512_bf16, dim3(4096), dim3(256), 0, stream,
                           hcur, sru_lng + (size_t)l * 512, sru_lnb + (size_t)l * 512, xnh, xnl);
        hipLaunchKernelGGL(gemm_split, dim3(1536 / 128, M_ / 128), dim3(256), 0, stream,
                           xnh, xnl, swh, swl, U, 1536, 512,
                           (const float*)nullptr, (const float*)nullptr);
        hipLaunchKernelGGL(sru_rec, dim3(128), dim3(64), 0, stream,
                           U, 1536, hcur, sru_wc + (size_t)l * 1024, sru_b + (size_t)l * 1024, hnxt);
        float* tmp = hcur; hcur = hnxt; hnxt = tmp;
    }
    // after 7 layers: hcur == hP (swh/swl now dead -> alias targets)

    // ---- LSTM pre-pipe: weight splits, gx0, ring/ctl init ----
    hipLaunchKernelGGL(conv_split, dim3(12288), dim3(256), 0, stream,
                       lstm_whh, whh3h, whh3l, 3 * 2048 * 512);
    hipLaunchKernelGGL(conv_split, dim3(8192), dim3(256), 0, stream,
                       lstm_wih + (size_t)2048 * 512, wih2h, wih2l, 2 * 2048 * 512);
    hipLaunchKernelGGL(conv_split, dim3(4096), dim3(256), 0, stream,
                       lstm_wih, wihh, wihl, 2048 * 512);
    hipLaunchKernelGGL(ln512_bf16, dim3(4096), dim3(256), 0, stream,
                       hcur, lstm_lng, lstm_lnb, xnh, xnl);
    hipLaunchKernelGGL(gemm_split, dim3(2048 / 128, M_ / 128), dim3(256), 0, stream,
                       xnh, xnl, wihh, wihl, gx, 2048, 512, lstm_bih, lstm_bhh);
    hipLaunchKernelGGL(sent_fill, dim3(144), dim3(256), 0, stream, rings, 3 * 3 * 4096);
    hipLaunchKernelGGL(sent_fill, dim3(1280), dim3(256), 0, stream, (unsigned*)gxr, 2 * GPH * 32768);
    hipLaunchKernelGGL(zero_ctl, dim3(1), dim3(256), 0, stream, ctl);

    // ---- pipelined 3-layer LSTM (one persistent kernel, 112 WGs) ----
    hipLaunchKernelGGL(lstm_pipe, dim3(112), dim3(256), 0, stream,
                       gx, whh3h, whh3l, wih2h, wih2l,
                       lstm_lng, lstm_lnb, lstm_bih, lstm_bhh,
                       hQ, rings, gxr, ctl);

    // ---- classifier ----
    hipLaunchKernelGGL(ln512_f32, dim3(4096), dim3(256), 0, stream, hQ, cls_lng, cls_lnb, (float*)U);
    hipLaunchKernelGGL(cls_gemm, dim3(2048), dim3(256), 0, stream, (const float*)U, cls_w, out);
}

// Round 15
// 7826.635 us; speedup vs baseline: 1.2480x; 1.0220x over previous
//
#include <hip/hip_runtime.h>
#include <stdint.h>
#include <stddef.h>

#define B_ 16
#define T_ 1024
#define F_ 80
#define D_ 512
#define M_ 16384   // T*B rows, row index = t*16 + b
#define VO 29      // V+1
#define SENT 0x7FC07FC0u
#define GPH 5      // gx-ring phases (sentinel-based, reset 1 ahead)

typedef float f32x4 __attribute__((ext_vector_type(4)));
typedef short s16x8 __attribute__((ext_vector_type(8)));
typedef unsigned short u16x8 __attribute__((ext_vector_type(8)));

static __device__ __forceinline__ unsigned short f2bf(float f) {
    union { float f; unsigned u; } v; v.f = f;
    unsigned r = v.u + 0x7FFFu + ((v.u >> 16) & 1u);
    return (unsigned short)(r >> 16);
}
static __device__ __forceinline__ float bf2f(unsigned short h) {
    union { unsigned u; float f; } v; v.u = ((unsigned)h) << 16; return v.f;
}
static __device__ __forceinline__ void split2(float v, unsigned short& hi, unsigned short& lo) {
    hi = f2bf(v);
    lo = f2bf(v - bf2f(hi));
}
static __device__ __forceinline__ float sigm(float x) {
    return 1.0f / (1.0f + __expf(-x));
}
static __device__ __forceinline__ float fast_tanh(float x) {
    return 1.0f - 2.0f / (__expf(2.0f * x) + 1.0f);
}
static __device__ __forceinline__ float wred(float v) {
    #pragma unroll
    for (int off = 1; off < 64; off <<= 1) v += __shfl_xor(v, off, 64);
    return v;
}
static __device__ __forceinline__ void stf_agent(float* p, float v) {
    union { float f; unsigned u; } c; c.f = v;
    __hip_atomic_store((unsigned*)p, c.u, __ATOMIC_RELAXED, __HIP_MEMORY_SCOPE_AGENT);
}
// async global->LDS, 16B per lane
static __device__ __forceinline__ void gload16(const void* g, void* lds) {
    __builtin_amdgcn_global_load_lds(
        (const __attribute__((address_space(1))) void*)g,
        (__attribute__((address_space(3))) void*)lds, 16, 0, 0);
}

// ---------------- weight conversion (fp32 -> bf16 hi/lo split) ----------------
__global__ __launch_bounds__(256) void conv_w0(const float* __restrict__ W,
        unsigned short* __restrict__ Bh, unsigned short* __restrict__ Bl) {
    int gid = blockIdx.x * 256 + threadIdx.x;     // 2048*96
    int n = gid / 96, k = gid - n * 96;
    float v = (k < 80) ? W[(size_t)k * 2048 + n] : 0.0f;
    unsigned short h, l; split2(v, h, l);
    Bh[gid] = h; Bl[gid] = l;
}
// pipe init: sentinel-fill rings + gxr, zero ctl (grid-stride)
__global__ __launch_bounds__(256) void pipe_init(unsigned* __restrict__ rings, int nring,
        unsigned* __restrict__ gxr, int ngx, unsigned* __restrict__ ctl) {
    int total = nring + ngx + 160;
    for (int i = blockIdx.x * 256 + threadIdx.x; i < total; i += gridDim.x * 256) {
        if (i < nring)
            __hip_atomic_store(&rings[i], SENT, __ATOMIC_RELAXED, __HIP_MEMORY_SCOPE_AGENT);
        else if (i < nring + ngx)
            __hip_atomic_store(&gxr[i - nring], SENT, __ATOMIC_RELAXED, __HIP_MEMORY_SCOPE_AGENT);
        else
            __hip_atomic_store(&ctl[i - nring - ngx], 0u, __ATOMIC_RELAXED, __HIP_MEMORY_SCOPE_AGENT);
    }
}

// ---------------- LayerNorm kernels ----------------
__global__ __launch_bounds__(256) void ln80_kernel(const float* __restrict__ x,
        const float* __restrict__ g, const float* __restrict__ bta,
        unsigned short* __restrict__ xh, unsigned short* __restrict__ xl) {
    int w = threadIdx.x >> 6, lane = threadIdx.x & 63;
    int row = blockIdx.x * 4 + w;          // row = t*16 + b
    int b = row & 15, t = row >> 4;
    const float* xr = x + ((size_t)b * T_ + t) * F_;
    float v0 = xr[lane];
    float v1 = (lane < 16) ? xr[64 + lane] : 0.0f;
    float mean = wred(v0 + v1) * (1.0f / 80.0f);
    float d0 = v0 - mean;
    float d1 = (lane < 16) ? (v1 - mean) : 0.0f;
    float var = wred(d0 * d0 + d1 * d1) * (1.0f / 80.0f);
    float rstd = rsqrtf(var + 1e-5f);
    float o0 = d0 * rstd * g[lane] + bta[lane];
    unsigned short h, l; split2(o0, h, l);
    xh[(size_t)row * 96 + lane] = h;
    xl[(size_t)row * 96 + lane] = l;
    if (lane < 32) {
        unsigned short hv = 0, lv = 0;
        if (lane < 16) {
            float o1 = d1 * rstd * g[64 + lane] + bta[64 + lane];
            split2(o1, hv, lv);
        }
        xh[(size_t)row * 96 + 64 + lane] = hv;
        xl[(size_t)row * 96 + 64 + lane] = lv;
    }
}

// LO=true: write hi+lo planes; LO=false: hi only (2-term GEMM consumers)
template <bool LO>
__global__ __launch_bounds__(256) void ln512_bf16(const float* __restrict__ hsrc,
        const float* __restrict__ g, const float* __restrict__ bta,
        unsigned short* __restrict__ oh, unsigned short* __restrict__ ol) {
    int w = threadIdx.x >> 6, lane = threadIdx.x & 63;
    size_t row = (size_t)blockIdx.x * 4 + w;
    const float* hr = hsrc + row * D_;
    float4 p0 = *(const float4*)(hr + lane * 8);
    float4 p1 = *(const float4*)(hr + lane * 8 + 4);
    float s = p0.x + p0.y + p0.z + p0.w + p1.x + p1.y + p1.z + p1.w;
    float mean = wred(s) * (1.0f / 512.0f);
    float d[8] = {p0.x - mean, p0.y - mean, p0.z - mean, p0.w - mean,
                  p1.x - mean, p1.y - mean, p1.z - mean, p1.w - mean};
    float q = 0.f;
    #pragma unroll
    for (int i = 0; i < 8; ++i) q += d[i] * d[i];
    float rstd = rsqrtf(wred(q) * (1.0f / 512.0f) + 1e-5f);
    const float* gp = g + lane * 8;
    const float* bp = bta + lane * 8;
    u16x8 vh, vl;
    #pragma unroll
    for (int i = 0; i < 8; ++i) {
        float o = d[i] * rstd * gp[i] + bp[i];
        unsigned short hh, ll; split2(o, hh, ll);
        vh[i] = hh; vl[i] = ll;
    }
    *(u16x8*)(oh + row * D_ + lane * 8) = vh;
    if (LO) *(u16x8*)(ol + row * D_ + lane * 8) = vl;
}

__global__ __launch_bounds__(256) void ln512_f32(const float* __restrict__ hsrc,
        const float* __restrict__ g, const float* __restrict__ bta,
        float* __restrict__ o) {
    int w = threadIdx.x >> 6, lane = threadIdx.x & 63;
    size_t row = (size_t)blockIdx.x * 4 + w;
    const float* hr = hsrc + row * D_;
    float4 p0 = *(const float4*)(hr + lane * 8);
    float4 p1 = *(const float4*)(hr + lane * 8 + 4);
    float s = p0.x + p0.y + p0.z + p0.w + p1.x + p1.y + p1.z + p1.w;
    float mean = wred(s) * (1.0f / 512.0f);
    float d[8] = {p0.x - mean, p0.y - mean, p0.z - mean, p0.w - mean,
                  p1.x - mean, p1.y - mean, p1.z - mean, p1.w - mean};
    float q = 0.f;
    #pragma unroll
    for (int i = 0; i < 8; ++i) q += d[i] * d[i];
    float rstd = rsqrtf(wred(q) * (1.0f / 512.0f) + 1e-5f);
    const float* gp = g + lane * 8;
    const float* bp = bta + lane * 8;
    float* op = o + row * D_ + lane * 8;
    #pragma unroll
    for (int i = 0; i < 8; ++i) op[i] = d[i] * rstd * gp[i] + bp[i];
}

// ------- split bf16 MFMA GEMM, 128x128 tile, global_load_lds + XOR swizzle -------
// TERMS=3: Ah*Bh + Al*Bh + Ah*Bl (fp32-accurate). TERMS=2: Ah*Bh + Ah*Bl
// (bf16 activations x exact weights) — used for SRU layers 1-7.
template <int TERMS>
__global__ __launch_bounds__(256) void gemm_split_t(
        const unsigned short* __restrict__ Ah, const unsigned short* __restrict__ Al,
        const unsigned short* __restrict__ Bh, const unsigned short* __restrict__ Bl,
        float* __restrict__ C, int N, int Kp,
        const float* __restrict__ bias0, const float* __restrict__ bias1) {
    __shared__ __align__(16) unsigned short sAh[4096];
    __shared__ __align__(16) unsigned short sAl[TERMS == 3 ? 4096 : 16];
    __shared__ __align__(16) unsigned short sBh[4096];
    __shared__ __align__(16) unsigned short sBl[4096];
    const int tid = threadIdx.x;
    const int wv = tid >> 6, lane = tid & 63;
    const int c_ = lane & 15, r_ = lane >> 4;
    const int wr = wv >> 1, wc = wv & 1;
    const int mBase = blockIdx.y * 128, nBase = blockIdx.x * 128;

    const int row0 = tid >> 2, row1 = 64 + row0;
    const int sp = tid & 3;
    const int x0 = (row0 & 3) ^ ((row0 >> 2) & 3);
    const int x1 = (row1 & 3) ^ ((row1 >> 2) & 3);
    const size_t gA0 = (size_t)(mBase + row0) * Kp + (size_t)((sp ^ x0) * 8);
    const size_t gA1 = (size_t)(mBase + row1) * Kp + (size_t)((sp ^ x1) * 8);
    const size_t gB0 = (size_t)(nBase + row0) * Kp + (size_t)((sp ^ x0) * 8);
    const size_t gB1 = (size_t)(nBase + row1) * Kp + (size_t)((sp ^ x1) * 8);
    const int ldsW = wv * 1024;

    int offA[4], offB[4];
    #pragma unroll
    for (int f = 0; f < 4; ++f) {
        int ra = wr * 64 + f * 16 + c_;
        int xa = (ra & 3) ^ ((ra >> 2) & 3);
        offA[f] = ra * 32 + ((r_ ^ xa) * 8);
        int rb = wc * 64 + f * 16 + c_;
        int xb = (rb & 3) ^ ((rb >> 2) & 3);
        offB[f] = rb * 32 + ((r_ ^ xb) * 8);
    }

    f32x4 acc[4][4] = {};
    for (int kt = 0; kt < Kp; kt += 32) {
        gload16(Ah + gA0 + kt, (char*)sAh + ldsW);
        gload16(Ah + gA1 + kt, (char*)sAh + 4096 + ldsW);
        if constexpr (TERMS == 3) {
            gload16(Al + gA0 + kt, (char*)sAl + ldsW);
            gload16(Al + gA1 + kt, (char*)sAl + 4096 + ldsW);
        }
        gload16(Bh + gB0 + kt, (char*)sBh + ldsW);
        gload16(Bh + gB1 + kt, (char*)sBh + 4096 + ldsW);
        gload16(Bl + gB0 + kt, (char*)sBl + ldsW);
        gload16(Bl + gB1 + kt, (char*)sBl + 4096 + ldsW);
        __syncthreads();
        s16x8 ah[4], al[4], bh[4], bl[4];
        #pragma unroll
        for (int f = 0; f < 4; ++f) {
            ah[f] = *(const s16x8*)&sAh[offA[f]];
            if constexpr (TERMS == 3) al[f] = *(const s16x8*)&sAl[offA[f]];
            bh[f] = *(const s16x8*)&sBh[offB[f]];
            bl[f] = *(const s16x8*)&sBl[offB[f]];
        }
        #pragma unroll
        for (int mf = 0; mf < 4; ++mf) {
            #pragma unroll
            for (int nf = 0; nf < 4; ++nf) {
                acc[mf][nf] = __builtin_amdgcn_mfma_f32_16x16x32_bf16(ah[mf], bh[nf], acc[mf][nf], 0, 0, 0);
                if constexpr (TERMS == 3)
                    acc[mf][nf] = __builtin_amdgcn_mfma_f32_16x16x32_bf16(al[mf], bh[nf], acc[mf][nf], 0, 0, 0);
                acc[mf][nf] = __builtin_amdgcn_mfma_f32_16x16x32_bf16(ah[mf], bl[nf], acc[mf][nf], 0, 0, 0);
            }
        }
        __syncthreads();
    }
    #pragma unroll
    for (int mf = 0; mf < 4; ++mf) {
        #pragma unroll
        for (int r = 0; r < 4; ++r) {
            int m = mBase + wr * 64 + mf * 16 + r_ * 4 + r;
            float* crow = C + (size_t)m * N + nBase + wc * 64;
            #pragma unroll
            for (int nf = 0; nf < 4; ++nf) {
                int n = nBase + wc * 64 + nf * 16 + c_;
                float v = acc[mf][nf][r];
                if (bias0) v += bias0[n];
                if (bias1) v += bias1[n];
                crow[nf * 16 + c_] = v;
            }
        }
    }
}

// ---------------- SRU recurrence + fused weight conversion ----------------
// blocks [0,128): 8192 independent (b,d) chains. blocks [128,2176): grid-stride
// conversion jobs (jobA = transpose sru_w (512,1536)->(1536,512) hi/lo;
// jobs B/C/D = row-major fp32 -> hi/lo). Conversions ride under the
// latency-bound recurrence for free.
__global__ __launch_bounds__(64) void sru_fused(const float* __restrict__ U, int NU,
        const float* __restrict__ xprev, const float* __restrict__ wc,
        const float* __restrict__ bias, float* __restrict__ hout,
        const float* __restrict__ sA, unsigned short* __restrict__ dAh,
        unsigned short* __restrict__ dAl, int nA,
        const float* __restrict__ sB, unsigned short* __restrict__ dBh,
        unsigned short* __restrict__ dBl, int nB,
        const float* __restrict__ sC, unsigned short* __restrict__ dCh,
        unsigned short* __restrict__ dCl, int nC,
        const float* __restrict__ sD, unsigned short* __restrict__ dDh,
        unsigned short* __restrict__ dDl, int nD) {
    const int bid = blockIdx.x;
    if (bid < 128) {
        int gid = bid * 64 + threadIdx.x;
        int d = gid & (D_ - 1), b = gid >> 9;
        float vf = wc[d], vr = wc[D_ + d];
        float bf = bias[d], br = bias[D_ + d];
        const float* u0 = U + d;
        const float* u1 = U + D_ + d;
        const float* u2 = U + 2 * D_ + d;
        const float* xr;  size_t xstride;
        if (xprev) { xr = xprev + d; xstride = D_; }
        else       { xr = U + 3 * (size_t)D_ + d; xstride = (size_t)NU; }
        float* ho = hout + d;
        float c = 0.f;
        #pragma unroll 4
        for (int t = 0; t < T_; ++t) {
            size_t row = (size_t)(t * 16 + b);
            float a0 = u0[row * NU];
            float a1 = u1[row * NU];
            float a2 = u2[row * NU];
            float xv = xr[row * xstride];
            float f = sigm(a1 + vf * c + bf);
            float r = sigm(a2 + vr * c + br);
            c = f * c + (1.f - f) * a0;
            float h = r * c + (1.f - r) * xv;
            ho[row * D_] = h;
        }
    } else {
        const int total = nA + nB + nC + nD;
        const int stride = (2176 - 128) * 64;
        for (int idx = (bid - 128) * 64 + threadIdx.x; idx < total; idx += stride) {
            float v; unsigned short *oh, *ol; int o;
            if (idx < nA) {
                int n = idx >> 9, k = idx & 511;
                v = sA[(size_t)k * 1536 + n]; oh = dAh; ol = dAl; o = idx;
            } else if (idx < nA + nB) {
                o = idx - nA; v = sB[o]; oh = dBh; ol = dBl;
            } else if (idx < nA + nB + nC) {
                o = idx - nA - nB; v = sC[o]; oh = dCh; ol = dCl;
            } else {
                o = idx - nA - nB - nC; v = sD[o]; oh = dDh; ol = dDl;
            }
            unsigned short h, l; split2(v, h, l);
            oh[o] = h; ol[o] = l;
        }
    }
}

// =================== 3-layer pipelined LSTM (persistent, 112 WGs) ===================
// (round-14 proven state: hi-only 3-phase h-rings, 5-slot gx sentinel rings)

template <int MODE>
static __device__ void lstm_role(int wg, const float* gxsrc,
        const unsigned short* Wh, const unsigned short* Wl,
        unsigned* ring, unsigned* myLprog,
        const unsigned* consCprog, float* hout) {
    __shared__ __align__(16) unsigned short hH[16][520];
    __shared__ float G[16][132];
    const int tid = threadIdx.x;
    const int w = tid >> 6, lane = tid & 63;
    const int c_ = lane & 15, r_ = lane >> 4;

    s16x8 bh0[16], bh1[16], bl0[16], bl1[16];
    {
        size_t R0 = (size_t)(w * 512 + wg * 32 + c_) * 512;
        size_t R1 = R0 + 16 * 512;
        #pragma unroll
        for (int ks = 0; ks < 16; ++ks) {
            bh0[ks] = *(const s16x8*)(Wh + R0 + ks * 32 + r_ * 8);
            bh1[ks] = *(const s16x8*)(Wh + R1 + ks * 32 + r_ * 8);
            bl0[ks] = *(const s16x8*)(Wl + R0 + ks * 32 + r_ * 8);
            bl1[ks] = *(const s16x8*)(Wl + R1 + ks * 32 + r_ * 8);
        }
    }
    for (int i = tid; i < 16 * 520; i += 256)
        ((unsigned short*)hH)[i] = 0;
    const int eb = tid >> 4;
    const int ed = (tid * 2) & 31;
    float cc0 = 0.f, cc1 = 0.f;
    const int col0 = w * 512 + wg * 32 + c_;
    const int hidx = (eb * 512 + wg * 32 + ed) >> 1;

    float gxv0[4], gxv1[4];
    if (MODE == 0) {
        #pragma unroll
        for (int r = 0; r < 4; ++r) {
            int bt = r_ * 4 + r;
            gxv0[r] = gxsrc[(size_t)bt * 2048 + col0];
            gxv1[r] = gxsrc[(size_t)bt * 2048 + col0 + 16];
        }
    } else {
        const float* gs = gxsrc;
        unsigned gv[8];
        unsigned gb = 0xFFu;
        while (true) {
            #pragma unroll
            for (int r = 0; r < 4; ++r) {
                int bt = r_ * 4 + r;
                if (gb & (1u << r))
                    gv[r] = __hip_atomic_load((const unsigned*)(gs + (size_t)bt * 2048 + col0),
                                              __ATOMIC_RELAXED, __HIP_MEMORY_SCOPE_AGENT);
                if (gb & (1u << (4 + r)))
                    gv[4 + r] = __hip_atomic_load((const unsigned*)(gs + (size_t)bt * 2048 + col0 + 16),
                                                  __ATOMIC_RELAXED, __HIP_MEMORY_SCOPE_AGENT);
            }
            unsigned nb = 0u;
            #pragma unroll
            for (int r = 0; r < 8; ++r)
                if ((gv[r] >> 16) == 0x7FC0u) nb |= 1u << r;
            gb = nb;
            if (!__any(gb != 0u)) break;
            __builtin_amdgcn_s_sleep(1);
        }
        #pragma unroll
        for (int r = 0; r < 4; ++r) {
            union { unsigned u; float f; } c0, c1;
            c0.u = gv[r]; c1.u = gv[4 + r];
            gxv0[r] = c0.f; gxv1[r] = c1.f;
        }
    }
    int pcur = 0, pnxt = 4096, pthr = 8192;   // hi-only: 4096 dwords/phase
    __syncthreads();

    for (int t = 0; t < T_; ++t) {
        if (MODE == 1 && tid == 0)
            __hip_atomic_store(&myLprog[wg], (unsigned)t, __ATOMIC_RELAXED, __HIP_MEMORY_SCOPE_AGENT);
        if (consCprog) {
            int lim = t - 1;
            while (true) {
                int p = (int)__hip_atomic_load(&consCprog[lane & 31],
                                               __ATOMIC_RELAXED, __HIP_MEMORY_SCOPE_AGENT);
                if (__all(p >= lim)) break;
                __builtin_amdgcn_s_sleep(2);
            }
        }
        __hip_atomic_store(&ring[pnxt + hidx], SENT, __ATOMIC_RELAXED, __HIP_MEMORY_SCOPE_AGENT);
        f32x4 acc0 = {0.f, 0.f, 0.f, 0.f};
        f32x4 acc1 = {0.f, 0.f, 0.f, 0.f};
        #pragma unroll
        for (int ks = 0; ks < 16; ++ks) {
            s16x8 ah = *(const s16x8*)&hH[c_][ks * 32 + r_ * 8];
            acc0 = __builtin_amdgcn_mfma_f32_16x16x32_bf16(ah, bh0[ks], acc0, 0, 0, 0);
            acc1 = __builtin_amdgcn_mfma_f32_16x16x32_bf16(ah, bh1[ks], acc1, 0, 0, 0);
            acc0 = __builtin_amdgcn_mfma_f32_16x16x32_bf16(ah, bl0[ks], acc0, 0, 0, 0);
            acc1 = __builtin_amdgcn_mfma_f32_16x16x32_bf16(ah, bl1[ks], acc1, 0, 0, 0);
        }
        #pragma unroll
        for (int r = 0; r < 4; ++r) {
            int bt = r_ * 4 + r;
            G[bt][w * 32 + c_]      = acc0[r] + gxv0[r];
            G[bt][w * 32 + 16 + c_] = acc1[r] + gxv1[r];
        }
        __syncthreads();
        float iv0 = G[eb][ed],     fv0 = G[eb][32 + ed], gv0 = G[eb][64 + ed], ov0 = G[eb][96 + ed];
        float iv1 = G[eb][ed + 1], fv1 = G[eb][33 + ed], gv1 = G[eb][65 + ed], ov1 = G[eb][97 + ed];
        cc0 = sigm(fv0) * cc0 + sigm(iv0) * fast_tanh(gv0);
        cc1 = sigm(fv1) * cc1 + sigm(iv1) * fast_tanh(gv1);
        float h0 = sigm(ov0) * fast_tanh(cc0);
        float h1 = sigm(ov1) * fast_tanh(cc1);
        asm volatile("s_waitcnt vmcnt(0)" ::: "memory");
        unsigned packH = (unsigned)f2bf(h0) | ((unsigned)f2bf(h1) << 16);
        __hip_atomic_store(&ring[pcur + hidx], packH, __ATOMIC_RELAXED, __HIP_MEMORY_SCOPE_AGENT);
        if (hout) {
            size_t orow = (size_t)(t * 16 + eb) * D_ + wg * 32 + ed;
            hout[orow] = h0; hout[orow + 1] = h1;
        }
        if (t == T_ - 1) break;
        if (MODE == 0) {
            const float* gxr = gxsrc + (size_t)((t + 1) * 16) * 2048;
            #pragma unroll
            for (int r = 0; r < 4; ++r) {
                int bt = r_ * 4 + r;
                gxv0[r] = gxr[(size_t)bt * 2048 + col0];
                gxv1[r] = gxr[(size_t)bt * 2048 + col0 + 16];
            }
        } else {
            const float* gs = gxsrc + (size_t)((t + 1) % GPH) * 32768;
            unsigned gv[8];
            unsigned gb = 0xFFu;
            while (true) {
                #pragma unroll
                for (int r = 0; r < 4; ++r) {
                    int bt = r_ * 4 + r;
                    if (gb & (1u << r))
                        gv[r] = __hip_atomic_load((const unsigned*)(gs + (size_t)bt * 2048 + col0),
                                                  __ATOMIC_RELAXED, __HIP_MEMORY_SCOPE_AGENT);
                    if (gb & (1u << (4 + r)))
                        gv[4 + r] = __hip_atomic_load((const unsigned*)(gs + (size_t)bt * 2048 + col0 + 16),
                                                      __ATOMIC_RELAXED, __HIP_MEMORY_SCOPE_AGENT);
                }
                unsigned nb = 0u;
                #pragma unroll
                for (int r = 0; r < 8; ++r)
                    if ((gv[r] >> 16) == 0x7FC0u) nb |= 1u << r;
                gb = nb;
                if (!__any(gb != 0u)) break;
                __builtin_amdgcn_s_sleep(1);
            }
            #pragma unroll
            for (int r = 0; r < 4; ++r) {
                union { unsigned u; float f; } c0, c1;
                c0.u = gv[r]; c1.u = gv[4 + r];
                gxv0[r] = c0.f; gxv1[r] = c1.f;
            }
        }
        unsigned long long vh[8];
        unsigned badm = 0xFFu;
        while (true) {
            #pragma unroll
            for (int j = 0; j < 8; ++j) {
                int q = pcur + j * 512 + tid * 2;
                if (badm & (1u << j))
                    vh[j] = __hip_atomic_load((const unsigned long long*)&ring[q],
                                              __ATOMIC_RELAXED, __HIP_MEMORY_SCOPE_AGENT);
            }
            unsigned nb = 0u;
            #pragma unroll
            for (int j = 0; j < 8; ++j) {
                unsigned a0 = (unsigned)vh[j], a1 = (unsigned)(vh[j] >> 32);
                if (((a0 >> 16) == 0x7FC0u) || ((a1 >> 16) == 0x7FC0u)) nb |= 1u << j;
            }
            badm = nb;
            if (!__any(badm != 0u)) break;
            __builtin_amdgcn_s_sleep(1);
        }
        #pragma unroll
        for (int j = 0; j < 8; ++j) {
            int q = j * 512 + tid * 2;
            int bb = q >> 8, dd = (q & 255) * 2;
            *(unsigned long long*)&hH[bb][dd] = vh[j];
        }
        __syncthreads();
        int tmp = pcur; pcur = pnxt; pnxt = pthr; pthr = tmp;
    }
}

static __device__ void crew_role(int cid, const unsigned* srcring, float* gxr,
        unsigned* cprog, const unsigned* lprog,
        const unsigned short* WihHp, const unsigned short* WihLp,
        const float* g, const float* bta,
        const float* bihp, const float* bhhp) {
    __shared__ __align__(16) unsigned short xnH[16][520];
    __shared__ __align__(16) unsigned short xnL[16][520];
    const int tid = threadIdx.x;
    const int w = tid >> 6, lane = tid & 63;
    const int c_ = lane & 15, r_ = lane >> 4;
    const int col = cid * 64 + w * 16 + c_;
    const int rr = w * 4 + r_;          // LN row owned by this lane

    s16x8 bfh[16], bfl[16];
    {
        const unsigned short* wrH = WihHp + (size_t)col * 512;
        const unsigned short* wrL = WihLp + (size_t)col * 512;
        #pragma unroll
        for (int ks = 0; ks < 16; ++ks) {
            bfh[ks] = *(const s16x8*)(wrH + ks * 32 + r_ * 8);
            bfl[ks] = *(const s16x8*)(wrL + ks * 32 + r_ * 8);
        }
    }
    const float bias = bihp[col] + bhhp[col];
    float lg[32], lb[32];
    #pragma unroll
    for (int j = 0; j < 32; ++j) { lg[j] = g[c_ * 32 + j]; lb[j] = bta[c_ * 32 + j]; }

    for (int t = 0; t < T_; ++t) {
        {
            int lim = t - 3;
            while (true) {
                int p = (int)__hip_atomic_load(&lprog[lane & 15],
                                               __ATOMIC_RELAXED, __HIP_MEMORY_SCOPE_AGENT);
                if (__all(p >= lim)) break;
                __builtin_amdgcn_s_sleep(2);
            }
        }
        {
            unsigned* rs = (unsigned*)(gxr + (size_t)((t + 1) % GPH) * 32768);
            #pragma unroll
            for (int r = 0; r < 4; ++r)
                __hip_atomic_store(&rs[(size_t)(r_ * 4 + r) * 2048 + col], SENT,
                                   __ATOMIC_RELAXED, __HIP_MEMORY_SCOPE_AGENT);
        }
        const unsigned* sb = srcring + (t % 3) * 4096;
        const int qi = rr * 256 + c_ * 16;
        unsigned long long vh[8];
        unsigned badm = 0xFFu;
        while (true) {
            #pragma unroll
            for (int j = 0; j < 8; ++j) {
                if (badm & (1u << j))
                    vh[j] = __hip_atomic_load((const unsigned long long*)&sb[qi + j * 2],
                                              __ATOMIC_RELAXED, __HIP_MEMORY_SCOPE_AGENT);
            }
            unsigned nb = 0u;
            #pragma unroll
            for (int j = 0; j < 8; ++j) {
                unsigned a0 = (unsigned)vh[j], a1 = (unsigned)(vh[j] >> 32);
                if (((a0 >> 16) == 0x7FC0u) || ((a1 >> 16) == 0x7FC0u)) nb |= 1u << j;
            }
            badm = nb;
            if (!__any(badm != 0u)) break;
            __builtin_amdgcn_s_sleep(1);
        }
        float x[32];
        #pragma unroll
        for (int k = 0; k < 8; ++k) {
            unsigned ah = (unsigned)vh[k], bh = (unsigned)(vh[k] >> 32);
            x[4 * k + 0] = bf2f((unsigned short)ah);
            x[4 * k + 1] = bf2f((unsigned short)(ah >> 16));
            x[4 * k + 2] = bf2f((unsigned short)bh);
            x[4 * k + 3] = bf2f((unsigned short)(bh >> 16));
        }
        float s = 0.f;
        #pragma unroll
        for (int j = 0; j < 32; ++j) s += x[j];
        #pragma unroll
        for (int m = 1; m < 16; m <<= 1) s += __shfl_xor(s, m, 64);
        float mean = s * (1.0f / 512.0f);
        float q = 0.f;
        #pragma unroll
        for (int j = 0; j < 32; ++j) { float d = x[j] - mean; q += d * d; }
        #pragma unroll
        for (int m = 1; m < 16; m <<= 1) q += __shfl_xor(q, m, 64);
        float rstd = rsqrtf(q * (1.0f / 512.0f) + 1e-5f);
        u16x8 ph[4], pl[4];
        #pragma unroll
        for (int j = 0; j < 32; ++j) {
            float o = (x[j] - mean) * rstd * lg[j] + lb[j];
            unsigned short hh, ll; split2(o, hh, ll);
            ph[j >> 3][j & 7] = (unsigned short)hh;
            pl[j >> 3][j & 7] = (unsigned short)ll;
        }
        #pragma unroll
        for (int jj = 0; jj < 4; ++jj) {
            *(u16x8*)&xnH[rr][c_ * 32 + jj * 8] = ph[jj];
            *(u16x8*)&xnL[rr][c_ * 32 + jj * 8] = pl[jj];
        }
        __syncthreads();
        if (tid == 0)
            __hip_atomic_store(&cprog[cid], (unsigned)(t + 1), __ATOMIC_RELAXED, __HIP_MEMORY_SCOPE_AGENT);
        f32x4 acc = {bias, bias, bias, bias};
        #pragma unroll
        for (int ks = 0; ks < 16; ++ks) {
            s16x8 axh = *(const s16x8*)&xnH[c_][ks * 32 + r_ * 8];
            s16x8 axl = *(const s16x8*)&xnL[c_][ks * 32 + r_ * 8];
            acc = __builtin_amdgcn_mfma_f32_16x16x32_bf16(axh, bfh[ks], acc, 0, 0, 0);
            acc = __builtin_amdgcn_mfma_f32_16x16x32_bf16(axl, bfh[ks], acc, 0, 0, 0);
            acc = __builtin_amdgcn_mfma_f32_16x16x32_bf16(axh, bfl[ks], acc, 0, 0, 0);
        }
        asm volatile("s_waitcnt vmcnt(0)" ::: "memory");
        float* gs = gxr + (size_t)(t % GPH) * 32768;
        #pragma unroll
        for (int r = 0; r < 4; ++r)
            stf_agent(gs + (size_t)(r_ * 4 + r) * 2048 + col, acc[r]);
        __syncthreads();
    }
}

__global__ __launch_bounds__(256, 1) void lstm_pipe(
        const float* __restrict__ gx0,
        const unsigned short* __restrict__ WhhH, const unsigned short* __restrict__ WhhL,
        const unsigned short* __restrict__ WihH, const unsigned short* __restrict__ WihL,
        const float* __restrict__ lng, const float* __restrict__ lnb,
        const float* __restrict__ bih, const float* __restrict__ bhh,
        float* __restrict__ hout,
        unsigned* __restrict__ rings,   // [3][3*4096]  (hi-only)
        float* __restrict__ gxr,        // [2][GPH*32768]
        unsigned* __restrict__ ctl) {   // Lp1[16]@64, Lp2[16]@80, Cp1[32]@96, Cp2[32]@128
    const int bid = blockIdx.x;
    const size_t WSL = (size_t)2048 * 512;
    const int RNG = 3 * 4096;
    if (bid < 16) {
        lstm_role<0>(bid, gx0, WhhH, WhhL, rings,
                     nullptr, ctl + 96, nullptr);
    } else if (bid < 32) {
        lstm_role<1>(bid - 16, gxr, WhhH + WSL, WhhL + WSL, rings + RNG,
                     ctl + 64, ctl + 128, nullptr);
    } else if (bid < 48) {
        lstm_role<1>(bid - 32, gxr + (size_t)GPH * 32768, WhhH + 2 * WSL, WhhL + 2 * WSL,
                     rings + 2 * RNG, ctl + 80, nullptr, hout);
    } else if (bid < 80) {
        crew_role(bid - 48, rings, gxr, ctl + 96, ctl + 64,
                  WihH, WihL, lng + 512, lnb + 512, bih + 2048, bhh + 2048);
    } else {
        crew_role(bid - 80, rings + RNG, gxr + (size_t)GPH * 32768, ctl + 128, ctl + 80,
                  WihH + WSL, WihL + WSL, lng + 1024, lnb + 1024, bih + 4096, bhh + 4096);
    }
}

// ---------------- classifier ----------------
__global__ __launch_bounds__(256) void cls_gemm(const float* __restrict__ xn,
        const float* __restrict__ wcls, float* __restrict__ out) {
    __shared__ float wl[512][32];
    int tid = threadIdx.x;
    for (int idx = tid; idx < 512 * VO; idx += 256) {
        int k = idx / VO, v = idx - k * VO;
        wl[k][v] = wcls[idx];
    }
    __syncthreads();
    int r8 = tid >> 5, v = tid & 31;
    int row = blockIdx.x * 8 + r8;
    if (v >= VO) return;
    const float* xr = xn + (size_t)row * D_;
    float acc = 0.f;
    #pragma unroll 8
    for (int k = 0; k < 512; ++k) acc += xr[k] * wl[k][v];
    int b = row & 15, t = row >> 4;
    out[((size_t)b * T_ + t) * VO + v] = acc;
}

// ------------------------------- launch ------------------------------------------
extern "C" void kernel_launch(void* const* d_in, const int* in_sizes, int n_in,
                              void* d_out, int out_size, void* d_ws, size_t ws_size,
                              hipStream_t stream) {
    const float* x        = (const float*)d_in[0];
    const float* sru_w0   = (const float*)d_in[1];
    const float* sru_wc0  = (const float*)d_in[2];
    const float* sru_b0   = (const float*)d_in[3];
    const float* sru_ln0g = (const float*)d_in[4];
    const float* sru_ln0b = (const float*)d_in[5];
    const float* sru_w    = (const float*)d_in[6];
    const float* sru_wc   = (const float*)d_in[7];
    const float* sru_b    = (const float*)d_in[8];
    const float* sru_lng  = (const float*)d_in[9];
    const float* sru_lnb  = (const float*)d_in[10];
    const float* lstm_lng = (const float*)d_in[11];
    const float* lstm_lnb = (const float*)d_in[12];
    const float* lstm_wih = (const float*)d_in[13];
    const float* lstm_whh = (const float*)d_in[14];
    const float* lstm_bih = (const float*)d_in[15];
    const float* lstm_bhh = (const float*)d_in[16];
    const float* cls_lng  = (const float*)d_in[17];
    const float* cls_lnb  = (const float*)d_in[18];
    const float* cls_w    = (const float*)d_in[19];
    float* out = (float*)d_out;

    char* ws = (char*)d_ws;
    size_t off = 0;
    auto alloc = [&](size_t bytes) -> void* {
        off = (off + 255) & ~(size_t)255;
        void* p = ws + off;
        off += bytes;
        return p;
    };
    float* U             = (float*)alloc((size_t)M_ * 1536 * 4);
    float* hP            = (float*)alloc((size_t)M_ * D_ * 4);     // contiguous after U
    float* hQ            = (float*)alloc((size_t)M_ * D_ * 4);
    unsigned short* xnh  = (unsigned short*)alloc((size_t)M_ * D_ * 2);
    unsigned short* xnl  = (unsigned short*)alloc((size_t)M_ * D_ * 2);
    unsigned short* w0h  = (unsigned short*)alloc((size_t)2048 * 96 * 2);
    unsigned short* w0l  = (unsigned short*)alloc((size_t)2048 * 96 * 2);
    unsigned short* swh  = (unsigned short*)alloc((size_t)1536 * 512 * 2);  // SRU per-layer reuse
    unsigned short* swl  = (unsigned short*)alloc((size_t)1536 * 512 * 2);
    unsigned short* wihh = (unsigned short*)alloc((size_t)2048 * 512 * 2);  // LSTM layer-0 wih
    unsigned short* wihl = (unsigned short*)alloc((size_t)2048 * 512 * 2);
    unsigned short* whh3h = (unsigned short*)alloc((size_t)3 * 2048 * 512 * 2);
    unsigned short* whh3l = (unsigned short*)alloc((size_t)3 * 2048 * 512 * 2);
    unsigned short* wih2h = (unsigned short*)alloc((size_t)2 * 2048 * 512 * 2);
    unsigned short* wih2l = (unsigned short*)alloc((size_t)2 * 2048 * 512 * 2);
    // rings/gxr/ctl alias the SRU weight buffers (dead after SRU layers)
    unsigned* rings = (unsigned*)swh;                              // 3*3*4096*4 = 144 KB < 1.5 MB
    float*    gxr   = (float*)swl;                                 // 2*GPH*32768*4 = 1.25 MB < 1.5 MB
    unsigned* ctl   = (unsigned*)(((char*)swh) + 3 * 3 * 4096 * 4);
    float* gx = U;   // 2048-wide gx0 spans [U | hP] contiguously

    const int WSL = 2048 * 512;          // elements per LSTM weight layer
    const int NSW = 1536 * 512;          // elements per SRU weight layer

    hipLaunchKernelGGL(conv_w0, dim3(768), dim3(256), 0, stream, sru_w0, w0h, w0l);

    // ---- SRU layer 0 (gx = [U|hP], output -> hQ) ----
    hipLaunchKernelGGL(ln80_kernel, dim3(4096), dim3(256), 0, stream, x, sru_ln0g, sru_ln0b, xnh, xnl);
    hipLaunchKernelGGL(gemm_split_t<3>, dim3(2048 / 128, M_ / 128), dim3(256), 0, stream,
                       xnh, xnl, w0h, w0l, gx, 2048, 96, (const float*)nullptr, (const float*)nullptr);
    // sru_rec(0) + conv: sruw layer1 + ALL LSTM weight splits
    hipLaunchKernelGGL(sru_fused, dim3(2176), dim3(64), 0, stream,
                       gx, 2048, (const float*)nullptr, sru_wc0, sru_b0, hQ,
                       sru_w, swh, swl, NSW,
                       lstm_whh, whh3h, whh3l, 3 * WSL,
                       lstm_wih, wihh, wihl, WSL,
                       lstm_wih + (size_t)WSL, wih2h, wih2l, 2 * WSL);

    float* hcur = hQ; float* hnxt = hP;
    // ---- SRU layers 1..7 (2-term GEMM; conv next layer's weights under sru_rec) ----
    for (int l = 0; l < 7; ++l) {
        hipLaunchKernelGGL(ln512_bf16<false>, dim3(4096), dim3(256), 0, stream,
                           hcur, sru_lng + (size_t)l * 512, sru_lnb + (size_t)l * 512, xnh, xnl);
        hipLaunchKernelGGL(gemm_split_t<2>, dim3(1536 / 128, M_ / 128), dim3(256), 0, stream,
                           xnh, xnh, swh, swl, U, 1536, 512,
                           (const float*)nullptr, (const float*)nullptr);
        int nA = (l < 6) ? NSW : 0;
        hipLaunchKernelGGL(sru_fused, dim3(2176), dim3(64), 0, stream,
                           U, 1536, hcur, sru_wc + (size_t)l * 1024, sru_b + (size_t)l * 1024, hnxt,
                           sru_w + (size_t)(l + 1) * NSW, swh, swl, nA,
                           lstm_whh, whh3h, whh3l, 0,
                           lstm_wih, wihh, wihl, 0,
                           lstm_wih, wih2h, wih2l, 0);
        float* tmp = hcur; hcur = hnxt; hnxt = tmp;
    }
    // after 8 sru launches: hcur == hP (swh/swl now dead -> alias targets)

    // ---- LSTM pre-pipe: gx0 GEMM + ring/ctl init ----
    hipLaunchKernelGGL(ln512_bf16<true>, dim3(4096), dim3(256), 0, stream,
                       hcur, lstm_lng, lstm_lnb, xnh, xnl);
    hipLaunchKernelGGL(gemm_split_t<3>, dim3(2048 / 128, M_ / 128), dim3(256), 0, stream,
                       xnh, xnl, wihh, wihl, gx, 2048, 512, lstm_bih, lstm_bhh);
    hipLaunchKernelGGL(pipe_init, dim3(1024), dim3(256), 0, stream,
                       rings, 3 * 3 * 4096, (unsigned*)gxr, 2 * GPH * 32768, ctl);

    // ---- pipelined 3-layer LSTM (one persistent kernel, 112 WGs) ----
    hipLaunchKernelGGL(lstm_pipe, dim3(112), dim3(256), 0, stream,
                       gx, whh3h, whh3l, wih2h, wih2l,
                       lstm_lng, lstm_lnb, lstm_bih, lstm_bhh,
                       hQ, rings, gxr, ctl);

    // ---- classifier ----
    hipLaunchKernelGGL(ln512_f32, dim3(4096), dim3(256), 0, stream, hQ, cls_lng, cls_lnb, (float*)U);
    hipLaunchKernelGGL(cls_gemm, dim3(2048), dim3(256), 0, stream, (const float*)U, cls_w, out);
}